// Round 1
// baseline (635.233 us; speedup 1.0000x reference)
//
#include <hip/hip_runtime.h>
#include <hip/hip_bf16.h>

#define DEVI __device__ __forceinline__

constexpr int B_   = 8;
constexpr int L_   = 4097;
constexpr int MTOT = B_ * L_;          // 32776 tokens
constexpr int DH   = 384;              // d_half
constexpr int NS   = 16;               // d_state
constexpr int CH   = 48;               // scan chunk length (48 -> 2064 blocks, ~16 waves/CU)
constexpr int NCH  = (L_ + CH - 1) / CH;  // 86 chunks (last has 17 tokens)

typedef __bf16 bf16x8 __attribute__((ext_vector_type(8)));
typedef float  f32x4  __attribute__((ext_vector_type(4)));

DEVI float bl(unsigned v) { return __uint_as_float(v << 16); }          // low bf16
DEVI float bh(unsigned v) { return __uint_as_float(v & 0xffff0000u); }  // high bf16
DEVI float bf(const __hip_bfloat16 x) { return __bfloat162float(x); }
DEVI unsigned short f2bu(float x) {
  __hip_bfloat16 b = __float2bfloat16(x);
  return *(unsigned short*)&b;
}
DEVI float u16f(const uint4& u, int j) {   // element j (0..7) of 8 packed bf16
  const unsigned w = (&u.x)[j >> 1];
  return (j & 1) ? bh(w) : bl(w);
}
DEVI bf16x8 pk8(const float4& a, const float4& b) {  // 8 fp32 -> packed bf16x8
  union { uint4 u; bf16x8 v; } o;
  o.u.x = f2bu(a.x) | ((unsigned)f2bu(a.y) << 16);
  o.u.y = f2bu(a.z) | ((unsigned)f2bu(a.w) << 16);
  o.u.z = f2bu(b.x) | ((unsigned)f2bu(b.y) << 16);
  o.u.w = f2bu(b.z) | ((unsigned)f2bu(b.w) << 16);
  return o.v;
}

// ---------------------------------------------------------------------------
// dtype detector: hidden_states ~ N(0,1). bf16 -> every even u16 has exponent
// field ~126; fp32 -> even u16 are mantissa bits (uniform). flag=1 -> bf16.
// ---------------------------------------------------------------------------
__global__ void flag_k(const void* hs, int* flagp) {
  if (threadIdx.x == 0 && blockIdx.x == 0) {
    const unsigned short* u = (const unsigned short*)hs;
    int ok = 1;
    for (int i = 0; i < 8; ++i) {
      const unsigned short v = u[2 * i];
      const int e = (v >> 7) & 0xFF;
      if (!(v == 0 || (e >= 100 && e <= 140))) ok = 0;
    }
    flagp[0] = ok;
  }
}

// ---------------------------------------------------------------------------
// perm normalizer: int64 storage has all odd int32 words zero (values<4096).
// ---------------------------------------------------------------------------
__global__ void perm_k(const int* p0, const int* p1, int* d0, int* d1) {
  __shared__ int s_or;
  const int* src = blockIdx.x ? p1 : p0;
  int*       dst = blockIdx.x ? d1 : d0;
  if (threadIdx.x == 0) s_or = 0;
  __syncthreads();
  int loc = 0;
  for (int i = threadIdx.x; i < 2048; i += 1024) loc |= src[2 * i + 1];
  atomicOr(&s_or, loc);
  __syncthreads();
  const bool is64 = (s_or == 0);
  for (int j = threadIdx.x; j < 4096; j += 1024)
    dst[j] = is64 ? (int)((const long long*)src)[j] : src[j];
}

// ---------------------------------------------------------------------------
// fused normalization of all 9 weight tensors to bf16 (one launch)
// ---------------------------------------------------------------------------
struct NormSet { const void* src[9]; void* dst[9]; int n[9]; };
__global__ void norm_all(NormSet s, const int* flagp) {
  const int idx = blockIdx.x * 256 + threadIdx.x;
  const int f = flagp[0];
#pragma unroll
  for (int t = 0; t < 9; ++t) {
    if (idx < s.n[t]) {
      __hip_bfloat16* d = (__hip_bfloat16*)s.dst[t];
      if (f) d[idx] = ((const __hip_bfloat16*)s.src[t])[idx];
      else   d[idx] = __float2bfloat16(((const float*)s.src[t])[idx]);
    }
  }
}

// ---------------------------------------------------------------------------
// Wcomb bf16 (512 x 384): rows 0..383 = dt_proj_w @ x_proj_w[0:24] (fused dt
// matrix), rows 384..415 = x_proj_w[24:56] (B then C), rows 416..511 = 0.
// ---------------------------------------------------------------------------
__global__ void prep_k(const __hip_bfloat16* __restrict__ dtw,
                       const __hip_bfloat16* __restrict__ xw,
                       __hip_bfloat16* __restrict__ wcomb) {
  const int idx = blockIdx.x * 256 + threadIdx.x;
  if (idx >= 512 * 384) return;
  const int n = idx / 384, k = idx - n * 384;
  float v = 0.f;
  if (n < 384) {
#pragma unroll
    for (int r = 0; r < 24; ++r) v += bf(dtw[n * 24 + r]) * bf(xw[r * 384 + k]);
  } else if (n < 416) {
    v = bf(xw[(24 + n - 384) * 384 + k]);
  }
  wcomb[idx] = __float2bfloat16(v);
}

// ---------------------------------------------------------------------------
// MFMA GEMM, LDS-FREE (round 8): C[m,n] = sum_k A[src(m),k] * W[n,k], K=384.
// The LDS-staged fragment is bit-identical to a 16B contiguous per-lane
// global load (af[i] = A[row][kt*32+quad*8..+7]), so fragments are loaded
// DIRECTLY from global: zero barriers, K fully unrolled (12 steps), loads
// folded to base+offset: immediates and software-pipelined by the compiler.
// Round-7 structure stalled ~700cyc/K-step on the vmcnt-draining barrier at
// 2.2 blocks/CU (MfmaUtil 6%). A-panel reuse across nt-blocks and W reuse
// now go through L2; a bijective XCD-contiguous tile remap (T1, m204 form)
// keeps all nt-blocks of one mt on ONE XCD's L2 (round-7 FETCH was 3x A:
// nt-fast dispatch scattered the 6 sharers over 6 XCDs).
// 128x128 tile, 4 waves x (4x4) 16x16x32 bf16 subtiles, 3 blocks/CU.
// ---------------------------------------------------------------------------
template<int AD, int GATHER, int EPI>
__global__ __launch_bounds__(256, 3)
void gemm_k(const void* __restrict__ Av, const __hip_bfloat16* __restrict__ W,
            void* __restrict__ e0, void* __restrict__ e1,
            const __hip_bfloat16* __restrict__ bias,
            const int* __restrict__ gidx, const int* __restrict__ flagp,
            int M, int N)
{
  const int tid  = threadIdx.x;
  const int lane = tid & 63;
  const int wv   = tid >> 6;
  const int wm   = wv >> 1, wn = wv & 1;
  const int lrow = lane & 15, quad = lane >> 4;
  const int fbf  = flagp[0];              // 1 = bf16 external storage

  // bijective XCD-contiguous tile remap: xcd = id%8 (HW round-robin); each
  // XCD gets a contiguous nid band -> same-mt nt-blocks co-resident on one L2
  const int NT = gridDim.x;
  const int nblocks = NT * (int)gridDim.y;
  const int id = blockIdx.y * NT + blockIdx.x;
  const int q8 = nblocks >> 3, r8 = nblocks & 7;
  const int xcd = id & 7, slot = id >> 3;
  const int nid = (xcd < r8 ? xcd * (q8 + 1)
                            : r8 * (q8 + 1) + (xcd - r8) * q8) + slot;
  const int mt = nid / NT, nt = nid - mt * NT;

  // per-lane fragment row offsets (element units)
  unsigned aoff[4];
  const __hip_bfloat16* bp[4];
#pragma unroll
  for (int i = 0; i < 4; ++i) {
    int r = mt * 128 + wm * 64 + i * 16 + lrow;
    if (r >= M) r = M - 1;                // tail tile: duplicate a valid row
    int src;
    if (GATHER) { const int b = r / L_, t = r - b * L_;
                  src = b * L_ + (t == 0 ? 0 : 1 + gidx[t - 1]); }
    else        { src = r; }
    aoff[i] = (unsigned)src * 384u + quad * 8;
    const int c = nt * 128 + wn * 64 + i * 16 + lrow;
    bp[i] = W + (size_t)c * 384 + quad * 8;
  }

  f32x4 acc[4][4] = {};

  if (AD == 1 && !fbf) {                  // fp32 A storage: load+convert in regs
    const float* ap = (const float*)Av;
#pragma unroll
    for (int kt = 0; kt < 12; ++kt) {
      bf16x8 af[4], bfr[4];
#pragma unroll
      for (int i = 0; i < 4; ++i) {
        const float4 f0 = *(const float4*)(ap + (size_t)aoff[i] + kt * 32);
        const float4 f1 = *(const float4*)(ap + (size_t)aoff[i] + kt * 32 + 4);
        af[i] = pk8(f0, f1);
      }
#pragma unroll
      for (int j = 0; j < 4; ++j)
        bfr[j] = *(const bf16x8*)(bp[j] + kt * 32);
#pragma unroll
      for (int i = 0; i < 4; ++i)
#pragma unroll
        for (int j = 0; j < 4; ++j)
          acc[i][j] = __builtin_amdgcn_mfma_f32_16x16x32_bf16(af[i], bfr[j], acc[i][j], 0, 0, 0);
    }
  } else {                                // bf16 A storage: direct 16B fragments
    const __hip_bfloat16* ap = (const __hip_bfloat16*)Av;
#pragma unroll
    for (int kt = 0; kt < 12; ++kt) {
      bf16x8 af[4], bfr[4];
#pragma unroll
      for (int i = 0; i < 4; ++i)
        af[i] = *(const bf16x8*)(ap + (size_t)aoff[i] + kt * 32);
#pragma unroll
      for (int j = 0; j < 4; ++j)
        bfr[j] = *(const bf16x8*)(bp[j] + kt * 32);
#pragma unroll
      for (int i = 0; i < 4; ++i)
#pragma unroll
        for (int j = 0; j < 4; ++j)
          acc[i][j] = __builtin_amdgcn_mfma_f32_16x16x32_bf16(af[i], bfr[j], acc[i][j], 0, 0, 0);
    }
  }

  // epilogue: D[reg] = C[row=(lane>>4)*4+reg][col=lane&15]  (m89-verified)
#pragma unroll
  for (int i = 0; i < 4; ++i) {
    const int row0 = mt * 128 + wm * 64 + i * 16 + quad * 4;
#pragma unroll
    for (int j = 0; j < 4; ++j) {
      const int col = nt * 128 + wn * 64 + j * 16 + lrow;
      if (col >= N) continue;
#pragma unroll
      for (int rg = 0; rg < 4; ++rg) {
        const int r = row0 + rg;
        if (r >= M) continue;
        const float v = acc[i][j][rg];
        if (EPI == 0) {          // in_proj: x half -> e0, z half -> e1 (bf16)
          if (col < 384) ((__hip_bfloat16*)e0)[(size_t)r * 384 + col] = __float2bfloat16(v);
          else           ((__hip_bfloat16*)e1)[(size_t)r * 384 + (col - 384)] = __float2bfloat16(v);
        } else if (EPI == 1) {   // dt: bias+softplus (bf16); B/C (fp32)
          if (col < 384) {
            const float x = v + bf(bias[col]);
            const float sp = (x > 20.f) ? x : log1pf(__expf(x));
            ((__hip_bfloat16*)e0)[(size_t)r * 384 + col] = __float2bfloat16(sp);
          } else if (col < 416) {
            ((float*)e1)[(size_t)r * 32 + (col - 384)] = v;
          }
        } else {                 // final out: dtype per runtime flag
          if (fbf) ((__hip_bfloat16*)e0)[(size_t)r * 384 + col] = __float2bfloat16(v);
          else     ((float*)e0)[(size_t)r * 384 + col] = v;
        }
      }
    }
  }
}

// ---------------------------------------------------------------------------
// depthwise conv k=4 (taps t-1..t+2) + silu on x half; 8 channels/thread.
// ---------------------------------------------------------------------------
__global__ void convx_k(const __hip_bfloat16* __restrict__ xh,
                        const __hip_bfloat16* __restrict__ cxw,
                        __hip_bfloat16* __restrict__ xc) {
  const int idx = blockIdx.x * 256 + threadIdx.x;
  if (idx >= MTOT * 48) return;
  const int g  = idx % 48;       // channel group (8 ch)
  const int rg = idx / 48;       // token row
  const int t  = rg % L_;
  const int c0 = g * 8;
  uint4 wv[4];                   // weights: channels c0..c0+7 x 4 taps
#pragma unroll
  for (int p = 0; p < 4; ++p) wv[p] = *(const uint4*)(cxw + c0 * 4 + p * 8);
  float acc[8] = {};
#pragma unroll
  for (int k = 0; k < 4; ++k) {
    const int tt = t + k - 1;
    if (tt < 0 || tt >= L_) continue;
    const uint4 u = *(const uint4*)(xh + (size_t)(rg + k - 1) * 384 + c0);
#pragma unroll
    for (int j = 0; j < 8; ++j) {
      const int e = j * 4 + k;                      // weight flat element
      acc[j] += u16f(wv[e >> 3], e & 7) * u16f(u, j);
    }
  }
  uint4 o;
#pragma unroll
  for (int p = 0; p < 4; ++p) {
    const float s0 = acc[2 * p]     / (1.f + __expf(-acc[2 * p]));
    const float s1 = acc[2 * p + 1] / (1.f + __expf(-acc[2 * p + 1]));
    (&o.x)[p] = f2bu(s0) | ((unsigned)f2bu(s1) << 16);
  }
  *(uint4*)(xc + (size_t)rg * 384 + c0) = o;
}

// ---------------------------------------------------------------------------
// scan phase 1: per (b, chunk, d) local scan with h0=0. Emits:
//   - y_local = C . h_local + D*x  (bf16, IN PLACE over xc -- same thread RMW)
//   - chunk decay P = exp2(sum(dt)*a2) and h_end into pbuf/hend.
// Identity used: h(t) = h_local(t) + cumP(t) (.) h_start, so phase 3 only
// needs a correction term.
// ---------------------------------------------------------------------------
__global__ __launch_bounds__(128)
void scan1_k(const __hip_bfloat16* __restrict__ dt, const float* __restrict__ bc,
             __hip_bfloat16* xcio,
             const __hip_bfloat16* __restrict__ alog,
             const __hip_bfloat16* __restrict__ dpar,
             float* __restrict__ pbuf, float* __restrict__ hend)
{
  __shared__ float lBC[CH * 32];
  const int blk = blockIdx.x;
  const int dt3 = blk % 3;
  const int c   = (blk / 3) % NCH;
  const int b   = blk / (3 * NCH);
  const int d   = dt3 * 128 + threadIdx.x;
  const int t0  = c * CH;
  const int r0  = b * L_ + t0;
  const int tmax = (L_ - t0 < CH) ? (L_ - t0) : CH;
  for (int i = threadIdx.x; i < tmax * 32; i += 128) lBC[i] = bc[(size_t)r0 * 32 + i];
  __syncthreads();

  float a2[16];
#pragma unroll
  for (int n = 0; n < 16; ++n)
    a2[n] = -1.4426950408889634f * __expf(bf(alog[d * 16 + n]));  // A * log2(e)
  float h[16];
#pragma unroll
  for (int n = 0; n < 16; ++n) h[n] = 0.f;
  float sdt = 0.f;
  const float Dd = bf(dpar[d]);

  for (int tt = 0; tt < tmax; ++tt) {
    const size_t r = (size_t)(r0 + tt);
    const float dtv = bf(dt[r * 384 + d]);
    const float xv  = bf(xcio[r * 384 + d]);
    sdt += dtv;
    const float dtx = dtv * xv;
    float y = 0.f;
#pragma unroll
    for (int n = 0; n < 16; ++n) {
      h[n] = h[n] * exp2f(dtv * a2[n]) + dtx * lBC[tt * 32 + n];
      y += h[n] * lBC[tt * 32 + 16 + n];
    }
    y += Dd * xv;
    xcio[r * 384 + d] = __float2bfloat16(y);   // y_local, in place over x
  }
  const size_t base = ((size_t)(c * 8 + b) * 16) * 384 + d;
#pragma unroll
  for (int n = 0; n < 16; ++n) {
    pbuf[base + n * 384] = exp2f(sdt * a2[n]);
    hend[base + n * 384] = h[n];
  }
}

// ---------------------------------------------------------------------------
// scan phase 2: cross-chunk scan per (b,d,n); rewrites pbuf with h_start
// ---------------------------------------------------------------------------
__global__ void scan2_k(float* __restrict__ pbuf, const float* __restrict__ hend) {
  const int tid = blockIdx.x * 256 + threadIdx.x;   // 49152 total
  const int d = tid % 384;
  const int n = (tid / 384) & 15;
  const int b = tid / 6144;
  float H = 0.f;
  for (int c = 0; c < NCH; ++c) {
    const size_t idx = ((size_t)(c * 8 + b) * 16 + n) * 384 + d;
    const float p = pbuf[idx];
    const float he = hend[idx];
    pbuf[idx] = H;
    H = p * H + he;
  }
}

// ---------------------------------------------------------------------------
// scan phase 3 (light): y(t) = y_local(t) + sum_n C(t,n)*exp2(sdt(t)*a2[n])*
// h_start[n]; then fused z-conv + silu gate. Writes IN PLACE over dt (dtyg).
// Only C is staged in LDS (B no longer needed here).
// ---------------------------------------------------------------------------
__global__ __launch_bounds__(128)
void scan3_k(__hip_bfloat16* dtyg, const float* __restrict__ bc,
             const __hip_bfloat16* __restrict__ yl,
             const __hip_bfloat16* __restrict__ zh,
             const __hip_bfloat16* __restrict__ czw,
             const __hip_bfloat16* __restrict__ alog,
             const float* __restrict__ hstart)
{
  __shared__ float lC[CH * 16];
  const int blk = blockIdx.x;
  const int dt3 = blk % 3;
  const int c   = (blk / 3) % NCH;
  const int b   = blk / (3 * NCH);
  const int d   = dt3 * 128 + threadIdx.x;
  const int t0  = c * CH;
  const int r0  = b * L_ + t0;
  const int tmax = (L_ - t0 < CH) ? (L_ - t0) : CH;
  for (int i = threadIdx.x; i < tmax * 16; i += 128)
    lC[i] = bc[(size_t)r0 * 32 + (i >> 4) * 32 + 16 + (i & 15)];
  __syncthreads();

  float a2[16];
#pragma unroll
  for (int n = 0; n < 16; ++n)
    a2[n] = -1.4426950408889634f * __expf(bf(alog[d * 16 + n]));
  float hs_[16];
  const size_t base = ((size_t)(c * 8 + b) * 16) * 384 + d;
#pragma unroll
  for (int n = 0; n < 16; ++n) hs_[n] = hstart[base + n * 384];
  float cw[4];
#pragma unroll
  for (int k = 0; k < 4; ++k) cw[k] = bf(czw[d * 4 + k]);

  float zm1 = (t0 - 1 >= 0) ? bf(zh[(size_t)(r0 - 1) * 384 + d]) : 0.f;
  float z0  = bf(zh[(size_t)r0 * 384 + d]);
  float zp1 = (t0 + 1 < L_) ? bf(zh[(size_t)(r0 + 1) * 384 + d]) : 0.f;
  float sdt = 0.f;

  for (int tt = 0; tt < tmax; ++tt) {
    const int t = t0 + tt;
    const size_t r = (size_t)(r0 + tt);
    const float zp2 = (t + 2 < L_) ? bf(zh[(r + 2) * 384 + d]) : 0.f;
    const float dtv = bf(dtyg[r * 384 + d]);
    sdt += dtv;
    float corr = 0.f;
#pragma unroll
    for (int n = 0; n < 16; ++n)
      corr += lC[tt * 16 + n] * hs_[n] * exp2f(sdt * a2[n]);
    const float y = bf(yl[r * 384 + d]) + corr;
    const float zc = cw[0] * zm1 + cw[1] * z0 + cw[2] * zp1 + cw[3] * zp2;
    const float zs = zc / (1.f + __expf(-zc));
    dtyg[r * 384 + d] = __float2bfloat16(y * zs);
    zm1 = z0; z0 = zp1; zp1 = zp2;
  }
}

// ---------------------------------------------------------------------------
extern "C" void kernel_launch(void* const* d_in, const int* in_sizes, int n_in,
                              void* d_out, int out_size, void* d_ws, size_t ws_size,
                              hipStream_t stream) {
  const void* hs   = d_in[0];
  const void* w_in = d_in[1];
  const void* cxw  = d_in[2];
  const void* czw  = d_in[3];
  const void* xw   = d_in[4];
  const void* dtw  = d_in[5];
  const void* dtb  = d_in[6];
  const void* alog = d_in[7];
  const void* dpar = d_in[8];
  const void* ow   = d_in[9];
  const int* perm  = (const int*)d_in[10];
  const int* permr = (const int*)d_in[11];

  char* ws = (char*)d_ws;
  size_t off = 0;
  auto alloc = [&](size_t nbytes) -> char* {
    char* p = ws + off;
    off += (nbytes + 255) & ~(size_t)255;
    return p;
  };
  int* flag              = (int*)alloc(256);
  int* nperm             = (int*)alloc(4096 * 4);
  int* npermr            = (int*)alloc(4096 * 4);
  __hip_bfloat16* w_inb  = (__hip_bfloat16*)alloc(294912 * 2);
  __hip_bfloat16* cxwb   = (__hip_bfloat16*)alloc(1536 * 2);
  __hip_bfloat16* czwb   = (__hip_bfloat16*)alloc(1536 * 2);
  __hip_bfloat16* xwb    = (__hip_bfloat16*)alloc(21504 * 2);
  __hip_bfloat16* dtwb   = (__hip_bfloat16*)alloc(9216 * 2);
  __hip_bfloat16* dtbb   = (__hip_bfloat16*)alloc(384 * 2);
  __hip_bfloat16* alogb  = (__hip_bfloat16*)alloc(6144 * 2);
  __hip_bfloat16* dparb  = (__hip_bfloat16*)alloc(384 * 2);
  __hip_bfloat16* owb    = (__hip_bfloat16*)alloc(147456 * 2);
  __hip_bfloat16* wcombb = (__hip_bfloat16*)alloc((size_t)512 * 384 * 2);
  __hip_bfloat16* zh     = (__hip_bfloat16*)alloc((size_t)MTOT * 384 * 2);  // 25.2 MB
  __hip_bfloat16* xc     = (__hip_bfloat16*)alloc((size_t)MTOT * 384 * 2);  // 25.2 MB
  __hip_bfloat16* dtyg   = (__hip_bfloat16*)alloc((size_t)MTOT * 384 * 2);  // 25.2 MB
  float*          bcf    = (float*)alloc((size_t)MTOT * 32 * 4);            // 4.2 MB
  // d_out as scratch: xh (bf16, dies at convx), then pbuf+hend (33.8 MB of 50.3)
  __hip_bfloat16* xh   = (__hip_bfloat16*)d_out;
  float*          pbuf = (float*)d_out;
  float*          hend = (float*)((char*)d_out + (size_t)NCH * B_ * NS * DH * 4);

  // 0) dtype + perm normalization
  flag_k<<<1, 64, 0, stream>>>(hs, flag);
  perm_k<<<2, 1024, 0, stream>>>(perm, permr, nperm, npermr);
  NormSet ns;
  ns.src[0] = w_in; ns.dst[0] = w_inb; ns.n[0] = 294912;
  ns.src[1] = ow;   ns.dst[1] = owb;   ns.n[1] = 147456;
  ns.src[2] = xw;   ns.dst[2] = xwb;   ns.n[2] = 21504;
  ns.src[3] = dtw;  ns.dst[3] = dtwb;  ns.n[3] = 9216;
  ns.src[4] = alog; ns.dst[4] = alogb; ns.n[4] = 6144;
  ns.src[5] = cxw;  ns.dst[5] = cxwb;  ns.n[5] = 1536;
  ns.src[6] = czw;  ns.dst[6] = czwb;  ns.n[6] = 1536;
  ns.src[7] = dtb;  ns.dst[7] = dtbb;  ns.n[7] = 384;
  ns.src[8] = dpar; ns.dst[8] = dparb; ns.n[8] = 384;
  norm_all<<<1152, 256, 0, stream>>>(ns, flag);
  // 1) fused dt/BC weight build
  prep_k<<<768, 256, 0, stream>>>(dtwb, xwb, wcombb);
  // 2) in_proj MFMA GEMM + perm gather -> xh (d_out), zh
  gemm_k<1, 1, 0><<<dim3(6, 257), 256, 0, stream>>>(
      hs, w_inb, xh, zh, nullptr, nperm, flag, MTOT, 768);
  // 3) depthwise conv + silu on x half (8 ch/thread)
  convx_k<<<(MTOT * 48 + 255) / 256, 256, 0, stream>>>(xh, cxwb, xc);
  // 4) fused dt (bias+softplus, bf16) and B/C (fp32) MFMA GEMM
  gemm_k<0, 0, 1><<<dim3(4, 257), 256, 0, stream>>>(
      xc, wcombb, dtyg, bcf, dtbb, nullptr, flag, MTOT, 512);
  // 5) chunked selective scan (y_local in phase 1; light correction phase 3)
  scan1_k<<<B_ * NCH * 3, 128, 0, stream>>>(dtyg, bcf, xc, alogb, dparb, pbuf, hend);
  scan2_k<<<192, 256, 0, stream>>>(pbuf, hend);
  scan3_k<<<B_ * NCH * 3, 128, 0, stream>>>(dtyg, bcf, xc, zh, czwb, alogb, pbuf);
  // 6) out_proj MFMA GEMM with inverse-perm gather -> final output
  gemm_k<0, 1, 2><<<dim3(3, 257), 256, 0, stream>>>(
      dtyg, owb, d_out, nullptr, nullptr, npermr, flag, MTOT, 384);
  (void)in_sizes; (void)n_in; (void)out_size; (void)ws_size;
}

// Round 2
// 494.788 us; speedup vs baseline: 1.2838x; 1.2838x over previous
//
#include <hip/hip_runtime.h>
#include <hip/hip_bf16.h>

#define DEVI __device__ __forceinline__

constexpr int B_   = 8;
constexpr int L_   = 4097;
constexpr int MTOT = B_ * L_;          // 32776 tokens
constexpr int DH   = 384;              // d_half
constexpr int NS   = 16;               // d_state
constexpr int CH   = 48;               // scan chunk length
constexpr int NCH  = (L_ + CH - 1) / CH;  // 86 chunks

typedef __bf16 bf16x8 __attribute__((ext_vector_type(8)));
typedef float  f32x4  __attribute__((ext_vector_type(4)));

DEVI float bl(unsigned v) { return __uint_as_float(v << 16); }          // low bf16
DEVI float bh(unsigned v) { return __uint_as_float(v & 0xffff0000u); }  // high bf16
DEVI float bf(const __hip_bfloat16 x) { return __bfloat162float(x); }
DEVI unsigned short f2bu(float x) {
  __hip_bfloat16 b = __float2bfloat16(x);
  return *(unsigned short*)&b;
}
DEVI float u16f(const uint4& u, int j) {   // element j (0..7) of 8 packed bf16
  const unsigned w = (&u.x)[j >> 1];
  return (j & 1) ? bh(w) : bl(w);
}

// global -> LDS direct (16B per lane). LDS dest must be wave-uniform + lane*16.
DEVI void gld16(const __hip_bfloat16* g, __hip_bfloat16* l) {
  __builtin_amdgcn_global_load_lds(
      (const __attribute__((address_space(1))) void*)g,
      (__attribute__((address_space(3))) void*)l, 16, 0, 0);
}

// ---------------------------------------------------------------------------
// dtype detector: hidden_states ~ N(0,1). bf16 -> every even u16 has exponent
// field ~126; fp32 -> even u16 are mantissa bits (uniform). flag=1 -> bf16.
// ---------------------------------------------------------------------------
__global__ void flag_k(const void* hs, int* flagp) {
  if (threadIdx.x == 0 && blockIdx.x == 0) {
    const unsigned short* u = (const unsigned short*)hs;
    int ok = 1;
    for (int i = 0; i < 8; ++i) {
      const unsigned short v = u[2 * i];
      const int e = (v >> 7) & 0xFF;
      if (!(v == 0 || (e >= 100 && e <= 140))) ok = 0;
    }
    flagp[0] = ok;
  }
}

// ---------------------------------------------------------------------------
// perm normalizer: int64 storage has all odd int32 words zero (values<4096).
// ---------------------------------------------------------------------------
__global__ void perm_k(const int* p0, const int* p1, int* d0, int* d1) {
  __shared__ int s_or;
  const int* src = blockIdx.x ? p1 : p0;
  int*       dst = blockIdx.x ? d1 : d0;
  if (threadIdx.x == 0) s_or = 0;
  __syncthreads();
  int loc = 0;
  for (int i = threadIdx.x; i < 2048; i += 1024) loc |= src[2 * i + 1];
  atomicOr(&s_or, loc);
  __syncthreads();
  const bool is64 = (s_or == 0);
  for (int j = threadIdx.x; j < 4096; j += 1024)
    dst[j] = is64 ? (int)((const long long*)src)[j] : src[j];
}

// ---------------------------------------------------------------------------
// fused normalization of all 9 weight tensors to bf16 (one launch)
// ---------------------------------------------------------------------------
struct NormSet { const void* src[9]; void* dst[9]; int n[9]; };
__global__ void norm_all(NormSet s, const int* flagp) {
  const int idx = blockIdx.x * 256 + threadIdx.x;
  const int f = flagp[0];
#pragma unroll
  for (int t = 0; t < 9; ++t) {
    if (idx < s.n[t]) {
      __hip_bfloat16* d = (__hip_bfloat16*)s.dst[t];
      if (f) d[idx] = ((const __hip_bfloat16*)s.src[t])[idx];
      else   d[idx] = __float2bfloat16(((const float*)s.src[t])[idx]);
    }
  }
}

// ---------------------------------------------------------------------------
// Wcomb bf16 (512 x 384): rows 0..383 = dt_proj_w @ x_proj_w[0:24] (fused dt
// matrix), rows 384..415 = x_proj_w[24:56] (B then C), rows 416..511 = 0.
// ---------------------------------------------------------------------------
__global__ void prep_k(const __hip_bfloat16* __restrict__ dtw,
                       const __hip_bfloat16* __restrict__ xw,
                       __hip_bfloat16* __restrict__ wcomb) {
  const int idx = blockIdx.x * 256 + threadIdx.x;
  if (idx >= 512 * 384) return;
  const int n = idx / 384, k = idx - n * 384;
  float v = 0.f;
  if (n < 384) {
#pragma unroll
    for (int r = 0; r < 24; ++r) v += bf(dtw[n * 24 + r]) * bf(xw[r * 384 + k]);
  } else if (n < 416) {
    v = bf(xw[(24 + n - 384) * 384 + k]);
  }
  wcomb[idx] = __float2bfloat16(v);
}

// ---------------------------------------------------------------------------
// cvt_k (round 9): fused perm-gather + dtype-normalize of hidden_states into
// bf16 hsb. Removes the gather AND the fp32 path from the in_proj GEMM so all
// GEMMs can stage A via global_load_lds (bf16, sequential rows).
// ---------------------------------------------------------------------------
__global__ void cvt_k(const void* __restrict__ hs, __hip_bfloat16* __restrict__ dst,
                      const int* __restrict__ gidx, const int* __restrict__ flagp) {
  const int idx = blockIdx.x * 256 + threadIdx.x;
  if (idx >= MTOT * 48) return;
  const int j = idx % 48;        // 8-elem group within row
  const int r = idx / 48;        // destination (reordered) token row
  const int b = r / L_, t = r - b * L_;
  const int src = b * L_ + (t == 0 ? 0 : 1 + gidx[t - 1]);
  uint4 o;
  if (flagp[0]) {
    o = *(const uint4*)((const __hip_bfloat16*)hs + (size_t)src * 384 + j * 8);
  } else {
    const float* f = (const float*)hs + (size_t)src * 384 + j * 8;
    const float4 f0 = *(const float4*)f;
    const float4 f1 = *(const float4*)(f + 4);
    o.x = f2bu(f0.x) | ((unsigned)f2bu(f0.y) << 16);
    o.y = f2bu(f0.z) | ((unsigned)f2bu(f0.w) << 16);
    o.z = f2bu(f1.x) | ((unsigned)f2bu(f1.y) << 16);
    o.w = f2bu(f1.z) | ((unsigned)f2bu(f1.w) << 16);
  }
  *(uint4*)(dst + (size_t)r * 384 + j * 8) = o;
}

// ---------------------------------------------------------------------------
// MFMA GEMM, m97 structure (round 9): C[m,n] = sum_k A[src(m),k] * W[n,k],
// K=384 = 12 x BK32. 128x128 tile, 4 waves x (4x4) 16x16x32 bf16 subtiles.
// Staging via __builtin_amdgcn_global_load_lds width=16 (no VGPR round-trip),
// single-buffered LDS, 2 barriers per K-step. The vmcnt drain at barrier-2 is
// covered by the other 2 resident blocks (3 blocks/CU, m114 overlap) -- this
// is the HW-verified 874-TF structure, vs round-8's latency-serialized direct
// loads (MfmaUtil 5.4%) and round-7's reg-staged pipeline (6%).
// Bijective XCD-contiguous tile remap kept from round-8 (FETCH 156->31 MB).
// ---------------------------------------------------------------------------
template<int GATHER, int EPI>
__global__ __launch_bounds__(256, 3)
void gemm_k(const __hip_bfloat16* __restrict__ A, const __hip_bfloat16* __restrict__ W,
            void* __restrict__ e0, void* __restrict__ e1,
            const __hip_bfloat16* __restrict__ bias,
            const int* __restrict__ gidx, const int* __restrict__ flagp,
            int M, int N)
{
  __shared__ __align__(16) __hip_bfloat16 lA[128 * 32];
  __shared__ __align__(16) __hip_bfloat16 lB[128 * 32];
  const int tid  = threadIdx.x;
  const int lane = tid & 63;
  const int wv   = tid >> 6;
  const int wm   = wv >> 1, wn = wv & 1;
  const int lrow = lane & 15, quad = lane >> 4;
  const int fbf  = flagp[0];              // 1 = bf16 external storage

  // bijective XCD-contiguous tile remap (m204 form): same-mt blocks land on
  // one XCD's L2 -> A panel fetched ~once per XCD band.
  const int NT = gridDim.x;
  const int nblocks = NT * (int)gridDim.y;
  const int id = blockIdx.y * NT + blockIdx.x;
  const int q8 = nblocks >> 3, r8 = nblocks & 7;
  const int xcd = id & 7, slot = id >> 3;
  const int nid = (xcd < r8 ? xcd * (q8 + 1)
                            : r8 * (q8 + 1) + (xcd - r8) * q8) + slot;
  const int mt = nid / NT, nt = nid - mt * NT;

  // staging: thread covers LDS flat idx {tid, 256+tid} x 16B; row = idx>>2,
  // kcol = (idx&3)*8. Global source is per-lane (gather ok); LDS dest is
  // wave-uniform + lane*16 (linear), as global_load_lds requires.
  const __hip_bfloat16* aSrc[2];
  const __hip_bfloat16* bSrc[2];
  __hip_bfloat16* aDst[2];
  __hip_bfloat16* bDst[2];
#pragma unroll
  for (int p = 0; p < 2; ++p) {
    const int row = p * 64 + (tid >> 2);   // tile row 0..127
    const int kc  = (tid & 3) * 8;         // element offset in BK=32
    int r = mt * 128 + row;
    if (r >= M) r = M - 1;                 // tail tile: duplicate a valid row
    int src;
    if (GATHER) { const int b = r / L_, t = r - b * L_;
                  src = b * L_ + (t == 0 ? 0 : 1 + gidx[t - 1]); }
    else        { src = r; }
    aSrc[p] = A + (size_t)src * 384 + kc;
    const int c = nt * 128 + row;          // N is a multiple of 128 for all 3
    bSrc[p] = W + (size_t)c * 384 + kc;
    aDst[p] = &lA[(p * 256 + tid) * 8];
    bDst[p] = &lB[(p * 256 + tid) * 8];
  }

  f32x4 acc[4][4] = {};

#pragma unroll
  for (int kt = 0; kt < 12; ++kt) {        // K = 12 * 32
    __syncthreads();                       // WAR: prior ds_reads done
#pragma unroll
    for (int p = 0; p < 2; ++p) gld16(aSrc[p] + kt * 32, aDst[p]);
#pragma unroll
    for (int p = 0; p < 2; ++p) gld16(bSrc[p] + kt * 32, bDst[p]);
    __syncthreads();                       // implicit vmcnt drain: staged data visible
    bf16x8 af[4], bfr[4];
#pragma unroll
    for (int i = 0; i < 4; ++i)
      af[i] = *reinterpret_cast<const bf16x8*>(&lA[(wm * 64 + i * 16 + lrow) * 32 + quad * 8]);
#pragma unroll
    for (int j = 0; j < 4; ++j)
      bfr[j] = *reinterpret_cast<const bf16x8*>(&lB[(wn * 64 + j * 16 + lrow) * 32 + quad * 8]);
#pragma unroll
    for (int i = 0; i < 4; ++i)
#pragma unroll
      for (int j = 0; j < 4; ++j)
        acc[i][j] = __builtin_amdgcn_mfma_f32_16x16x32_bf16(af[i], bfr[j], acc[i][j], 0, 0, 0);
  }

  // epilogue: D[reg] = C[row=(lane>>4)*4+reg][col=lane&15]  (m89-verified)
#pragma unroll
  for (int i = 0; i < 4; ++i) {
    const int row0 = mt * 128 + wm * 64 + i * 16 + quad * 4;
#pragma unroll
    for (int j = 0; j < 4; ++j) {
      const int col = nt * 128 + wn * 64 + j * 16 + lrow;
      if (col >= N) continue;
#pragma unroll
      for (int rg = 0; rg < 4; ++rg) {
        const int r = row0 + rg;
        if (r >= M) continue;
        const float v = acc[i][j][rg];
        if (EPI == 0) {          // in_proj: x half -> e0, z half -> e1 (bf16)
          if (col < 384) ((__hip_bfloat16*)e0)[(size_t)r * 384 + col] = __float2bfloat16(v);
          else           ((__hip_bfloat16*)e1)[(size_t)r * 384 + (col - 384)] = __float2bfloat16(v);
        } else if (EPI == 1) {   // dt: bias+softplus (bf16); B/C (fp32)
          if (col < 384) {
            const float x = v + bf(bias[col]);
            const float sp = (x > 20.f) ? x : log1pf(__expf(x));
            ((__hip_bfloat16*)e0)[(size_t)r * 384 + col] = __float2bfloat16(sp);
          } else if (col < 416) {
            ((float*)e1)[(size_t)r * 32 + (col - 384)] = v;
          }
        } else {                 // final out: dtype per runtime flag
          if (fbf) ((__hip_bfloat16*)e0)[(size_t)r * 384 + col] = __float2bfloat16(v);
          else     ((float*)e0)[(size_t)r * 384 + col] = v;
        }
      }
    }
  }
}

// ---------------------------------------------------------------------------
// depthwise conv k=4 (taps t-1..t+2) + silu on x half; 8 channels/thread.
// ---------------------------------------------------------------------------
__global__ void convx_k(const __hip_bfloat16* __restrict__ xh,
                        const __hip_bfloat16* __restrict__ cxw,
                        __hip_bfloat16* __restrict__ xc) {
  const int idx = blockIdx.x * 256 + threadIdx.x;
  if (idx >= MTOT * 48) return;
  const int g  = idx % 48;       // channel group (8 ch)
  const int rg = idx / 48;       // token row
  const int t  = rg % L_;
  const int c0 = g * 8;
  uint4 wv[4];                   // weights: channels c0..c0+7 x 4 taps
#pragma unroll
  for (int p = 0; p < 4; ++p) wv[p] = *(const uint4*)(cxw + c0 * 4 + p * 8);
  float acc[8] = {};
#pragma unroll
  for (int k = 0; k < 4; ++k) {
    const int tt = t + k - 1;
    if (tt < 0 || tt >= L_) continue;
    const uint4 u = *(const uint4*)(xh + (size_t)(rg + k - 1) * 384 + c0);
#pragma unroll
    for (int j = 0; j < 8; ++j) {
      const int e = j * 4 + k;                      // weight flat element
      acc[j] += u16f(wv[e >> 3], e & 7) * u16f(u, j);
    }
  }
  uint4 o;
#pragma unroll
  for (int p = 0; p < 4; ++p) {
    const float s0 = acc[2 * p]     / (1.f + __expf(-acc[2 * p]));
    const float s1 = acc[2 * p + 1] / (1.f + __expf(-acc[2 * p + 1]));
    (&o.x)[p] = f2bu(s0) | ((unsigned)f2bu(s1) << 16);
  }
  *(uint4*)(xc + (size_t)rg * 384 + c0) = o;
}

// ---------------------------------------------------------------------------
// scan phase 1: per (b, chunk, d) local scan with h0=0. Emits:
//   - y_local = C . h_local + D*x  (bf16, IN PLACE over xc -- same thread RMW)
//   - chunk decay P = exp2(sum(dt)*a2) and h_end into pbuf/hend.
// ---------------------------------------------------------------------------
__global__ __launch_bounds__(128)
void scan1_k(const __hip_bfloat16* __restrict__ dt, const float* __restrict__ bc,
             __hip_bfloat16* xcio,
             const __hip_bfloat16* __restrict__ alog,
             const __hip_bfloat16* __restrict__ dpar,
             float* __restrict__ pbuf, float* __restrict__ hend)
{
  __shared__ float lBC[CH * 32];
  const int blk = blockIdx.x;
  const int dt3 = blk % 3;
  const int c   = (blk / 3) % NCH;
  const int b   = blk / (3 * NCH);
  const int d   = dt3 * 128 + threadIdx.x;
  const int t0  = c * CH;
  const int r0  = b * L_ + t0;
  const int tmax = (L_ - t0 < CH) ? (L_ - t0) : CH;
  for (int i = threadIdx.x; i < tmax * 32; i += 128) lBC[i] = bc[(size_t)r0 * 32 + i];
  __syncthreads();

  float a2[16];
#pragma unroll
  for (int n = 0; n < 16; ++n)
    a2[n] = -1.4426950408889634f * __expf(bf(alog[d * 16 + n]));  // A * log2(e)
  float h[16];
#pragma unroll
  for (int n = 0; n < 16; ++n) h[n] = 0.f;
  float sdt = 0.f;
  const float Dd = bf(dpar[d]);

  for (int tt = 0; tt < tmax; ++tt) {
    const size_t r = (size_t)(r0 + tt);
    const float dtv = bf(dt[r * 384 + d]);
    const float xv  = bf(xcio[r * 384 + d]);
    sdt += dtv;
    const float dtx = dtv * xv;
    float y = 0.f;
#pragma unroll
    for (int n = 0; n < 16; ++n) {
      h[n] = h[n] * exp2f(dtv * a2[n]) + dtx * lBC[tt * 32 + n];
      y += h[n] * lBC[tt * 32 + 16 + n];
    }
    y += Dd * xv;
    xcio[r * 384 + d] = __float2bfloat16(y);   // y_local, in place over x
  }
  const size_t base = ((size_t)(c * 8 + b) * 16) * 384 + d;
#pragma unroll
  for (int n = 0; n < 16; ++n) {
    pbuf[base + n * 384] = exp2f(sdt * a2[n]);
    hend[base + n * 384] = h[n];
  }
}

// ---------------------------------------------------------------------------
// scan phase 2: cross-chunk scan per (b,d,n); rewrites pbuf with h_start
// ---------------------------------------------------------------------------
__global__ void scan2_k(float* __restrict__ pbuf, const float* __restrict__ hend) {
  const int tid = blockIdx.x * 256 + threadIdx.x;   // 49152 total
  const int d = tid % 384;
  const int n = (tid / 384) & 15;
  const int b = tid / 6144;
  float H = 0.f;
  for (int c = 0; c < NCH; ++c) {
    const size_t idx = ((size_t)(c * 8 + b) * 16 + n) * 384 + d;
    const float p = pbuf[idx];
    const float he = hend[idx];
    pbuf[idx] = H;
    H = p * H + he;
  }
}

// ---------------------------------------------------------------------------
// scan phase 3 (light): y(t) = y_local(t) + sum_n C(t,n)*exp2(sdt(t)*a2[n])*
// h_start[n]; then fused z-conv + silu gate. Writes IN PLACE over dt (dtyg).
// ---------------------------------------------------------------------------
__global__ __launch_bounds__(128)
void scan3_k(__hip_bfloat16* dtyg, const float* __restrict__ bc,
             const __hip_bfloat16* __restrict__ yl,
             const __hip_bfloat16* __restrict__ zh,
             const __hip_bfloat16* __restrict__ czw,
             const __hip_bfloat16* __restrict__ alog,
             const float* __restrict__ hstart)
{
  __shared__ float lC[CH * 16];
  const int blk = blockIdx.x;
  const int dt3 = blk % 3;
  const int c   = (blk / 3) % NCH;
  const int b   = blk / (3 * NCH);
  const int d   = dt3 * 128 + threadIdx.x;
  const int t0  = c * CH;
  const int r0  = b * L_ + t0;
  const int tmax = (L_ - t0 < CH) ? (L_ - t0) : CH;
  for (int i = threadIdx.x; i < tmax * 16; i += 128)
    lC[i] = bc[(size_t)r0 * 32 + (i >> 4) * 32 + 16 + (i & 15)];
  __syncthreads();

  float a2[16];
#pragma unroll
  for (int n = 0; n < 16; ++n)
    a2[n] = -1.4426950408889634f * __expf(bf(alog[d * 16 + n]));
  float hs_[16];
  const size_t base = ((size_t)(c * 8 + b) * 16) * 384 + d;
#pragma unroll
  for (int n = 0; n < 16; ++n) hs_[n] = hstart[base + n * 384];
  float cw[4];
#pragma unroll
  for (int k = 0; k < 4; ++k) cw[k] = bf(czw[d * 4 + k]);

  float zm1 = (t0 - 1 >= 0) ? bf(zh[(size_t)(r0 - 1) * 384 + d]) : 0.f;
  float z0  = bf(zh[(size_t)r0 * 384 + d]);
  float zp1 = (t0 + 1 < L_) ? bf(zh[(size_t)(r0 + 1) * 384 + d]) : 0.f;
  float sdt = 0.f;

  for (int tt = 0; tt < tmax; ++tt) {
    const int t = t0 + tt;
    const size_t r = (size_t)(r0 + tt);
    const float zp2 = (t + 2 < L_) ? bf(zh[(r + 2) * 384 + d]) : 0.f;
    const float dtv = bf(dtyg[r * 384 + d]);
    sdt += dtv;
    float corr = 0.f;
#pragma unroll
    for (int n = 0; n < 16; ++n)
      corr += lC[tt * 16 + n] * hs_[n] * exp2f(sdt * a2[n]);
    const float y = bf(yl[r * 384 + d]) + corr;
    const float zc = cw[0] * zm1 + cw[1] * z0 + cw[2] * zp1 + cw[3] * zp2;
    const float zs = zc / (1.f + __expf(-zc));
    dtyg[r * 384 + d] = __float2bfloat16(y * zs);
    zm1 = z0; z0 = zp1; zp1 = zp2;
  }
}

// ---------------------------------------------------------------------------
extern "C" void kernel_launch(void* const* d_in, const int* in_sizes, int n_in,
                              void* d_out, int out_size, void* d_ws, size_t ws_size,
                              hipStream_t stream) {
  const void* hs   = d_in[0];
  const void* w_in = d_in[1];
  const void* cxw  = d_in[2];
  const void* czw  = d_in[3];
  const void* xw   = d_in[4];
  const void* dtw  = d_in[5];
  const void* dtb  = d_in[6];
  const void* alog = d_in[7];
  const void* dpar = d_in[8];
  const void* ow   = d_in[9];
  const int* perm  = (const int*)d_in[10];
  const int* permr = (const int*)d_in[11];

  char* ws = (char*)d_ws;
  size_t off = 0;
  auto alloc = [&](size_t nbytes) -> char* {
    char* p = ws + off;
    off += (nbytes + 255) & ~(size_t)255;
    return p;
  };
  int* flag              = (int*)alloc(256);
  int* nperm             = (int*)alloc(4096 * 4);
  int* npermr            = (int*)alloc(4096 * 4);
  __hip_bfloat16* w_inb  = (__hip_bfloat16*)alloc(294912 * 2);
  __hip_bfloat16* cxwb   = (__hip_bfloat16*)alloc(1536 * 2);
  __hip_bfloat16* czwb   = (__hip_bfloat16*)alloc(1536 * 2);
  __hip_bfloat16* xwb    = (__hip_bfloat16*)alloc(21504 * 2);
  __hip_bfloat16* dtwb   = (__hip_bfloat16*)alloc(9216 * 2);
  __hip_bfloat16* dtbb   = (__hip_bfloat16*)alloc(384 * 2);
  __hip_bfloat16* alogb  = (__hip_bfloat16*)alloc(6144 * 2);
  __hip_bfloat16* dparb  = (__hip_bfloat16*)alloc(384 * 2);
  __hip_bfloat16* owb    = (__hip_bfloat16*)alloc(147456 * 2);
  __hip_bfloat16* wcombb = (__hip_bfloat16*)alloc((size_t)512 * 384 * 2);
  __hip_bfloat16* hsb    = (__hip_bfloat16*)alloc((size_t)MTOT * 384 * 2);  // 25.2 MB
  __hip_bfloat16* zh     = (__hip_bfloat16*)alloc((size_t)MTOT * 384 * 2);  // 25.2 MB
  __hip_bfloat16* xc     = (__hip_bfloat16*)alloc((size_t)MTOT * 384 * 2);  // 25.2 MB
  __hip_bfloat16* dtyg   = (__hip_bfloat16*)alloc((size_t)MTOT * 384 * 2);  // 25.2 MB
  float*          bcf    = (float*)alloc((size_t)MTOT * 32 * 4);            // 4.2 MB
  // d_out as scratch: xh (bf16, dies at convx), then pbuf+hend (33.8 MB of 50.3)
  __hip_bfloat16* xh   = (__hip_bfloat16*)d_out;
  float*          pbuf = (float*)d_out;
  float*          hend = (float*)((char*)d_out + (size_t)NCH * B_ * NS * DH * 4);

  // 0) dtype + perm normalization
  flag_k<<<1, 64, 0, stream>>>(hs, flag);
  perm_k<<<2, 1024, 0, stream>>>(perm, permr, nperm, npermr);
  NormSet ns;
  ns.src[0] = w_in; ns.dst[0] = w_inb; ns.n[0] = 294912;
  ns.src[1] = ow;   ns.dst[1] = owb;   ns.n[1] = 147456;
  ns.src[2] = xw;   ns.dst[2] = xwb;   ns.n[2] = 21504;
  ns.src[3] = dtw;  ns.dst[3] = dtwb;  ns.n[3] = 9216;
  ns.src[4] = alog; ns.dst[4] = alogb; ns.n[4] = 6144;
  ns.src[5] = cxw;  ns.dst[5] = cxwb;  ns.n[5] = 1536;
  ns.src[6] = czw;  ns.dst[6] = czwb;  ns.n[6] = 1536;
  ns.src[7] = dtb;  ns.dst[7] = dtbb;  ns.n[7] = 384;
  ns.src[8] = dpar; ns.dst[8] = dparb; ns.n[8] = 384;
  norm_all<<<1152, 256, 0, stream>>>(ns, flag);
  // 1) fused dt/BC weight build
  prep_k<<<768, 256, 0, stream>>>(dtwb, xwb, wcombb);
  // 2) fused perm-gather + bf16 convert of hidden_states
  cvt_k<<<(MTOT * 48 + 255) / 256, 256, 0, stream>>>(hs, hsb, nperm, flag);
  // 3) in_proj MFMA GEMM (m97 structure) -> xh (d_out), zh
  gemm_k<0, 0><<<dim3(6, 257), 256, 0, stream>>>(
      hsb, w_inb, xh, zh, nullptr, nullptr, flag, MTOT, 768);
  // 4) depthwise conv + silu on x half (8 ch/thread)
  convx_k<<<(MTOT * 48 + 255) / 256, 256, 0, stream>>>(xh, cxwb, xc);
  // 5) fused dt (bias+softplus, bf16) and B/C (fp32) MFMA GEMM
  gemm_k<0, 1><<<dim3(4, 257), 256, 0, stream>>>(
      xc, wcombb, dtyg, bcf, dtbb, nullptr, flag, MTOT, 512);
  // 6) chunked selective scan (y_local in phase 1; light correction phase 3)
  scan1_k<<<B_ * NCH * 3, 128, 0, stream>>>(dtyg, bcf, xc, alogb, dparb, pbuf, hend);
  scan2_k<<<192, 256, 0, stream>>>(pbuf, hend);
  scan3_k<<<B_ * NCH * 3, 128, 0, stream>>>(dtyg, bcf, xc, zh, czwb, alogb, pbuf);
  // 7) out_proj MFMA GEMM with inverse-perm gather -> final output
  gemm_k<1, 2><<<dim3(3, 257), 256, 0, stream>>>(
      dtyg, owb, d_out, nullptr, nullptr, npermr, flag, MTOT, 384);
  (void)in_sizes; (void)n_in; (void)out_size; (void)ws_size;
}

// Round 3
// 423.201 us; speedup vs baseline: 1.5010x; 1.1692x over previous
//
#include <hip/hip_runtime.h>
#include <hip/hip_bf16.h>

#define DEVI __device__ __forceinline__

constexpr int B_   = 8;
constexpr int L_   = 4097;
constexpr int MTOT = B_ * L_;          // 32776 tokens
constexpr int DH   = 384;              // d_half
constexpr int NS   = 16;               // d_state
constexpr int CH   = 48;               // scan chunk length
constexpr int NCH  = (L_ + CH - 1) / CH;  // 86 chunks

typedef __bf16 bf16x8 __attribute__((ext_vector_type(8)));
typedef float  f32x4  __attribute__((ext_vector_type(4)));

DEVI float bl(unsigned v) { return __uint_as_float(v << 16); }          // low bf16
DEVI float bh(unsigned v) { return __uint_as_float(v & 0xffff0000u); }  // high bf16
DEVI float bf(const __hip_bfloat16 x) { return __bfloat162float(x); }
DEVI unsigned short f2bu(float x) {
  __hip_bfloat16 b = __float2bfloat16(x);
  return *(unsigned short*)&b;
}
DEVI float u16f(const uint4& u, int j) {   // element j (0..7) of 8 packed bf16
  const unsigned w = (&u.x)[j >> 1];
  return (j & 1) ? bh(w) : bl(w);
}

// global -> LDS direct (16B per lane). LDS dest must be wave-uniform + lane*16.
DEVI void gld16(const __hip_bfloat16* g, __hip_bfloat16* l) {
  __builtin_amdgcn_global_load_lds(
      (const __attribute__((address_space(1))) void*)g,
      (__attribute__((address_space(3))) void*)l, 16, 0, 0);
}

// ---------------------------------------------------------------------------
// dtype detector: hidden_states ~ N(0,1). bf16 -> every even u16 has exponent
// field ~126; fp32 -> even u16 are mantissa bits (uniform). flag=1 -> bf16.
// flag[1] = geometric-A structure flag (init 1, cleared by a2prep_k).
// ---------------------------------------------------------------------------
__global__ void flag_k(const void* hs, int* flagp) {
  if (threadIdx.x == 0 && blockIdx.x == 0) {
    const unsigned short* u = (const unsigned short*)hs;
    int ok = 1;
    for (int i = 0; i < 8; ++i) {
      const unsigned short v = u[2 * i];
      const int e = (v >> 7) & 0xFF;
      if (!(v == 0 || (e >= 100 && e <= 140))) ok = 0;
    }
    flagp[0] = ok;
    flagp[1] = 1;
  }
}

// ---------------------------------------------------------------------------
// a2prep_k: a2[d][n] = -log2(e)*exp(A_log[d][n]) in fp32, plus structure
// check a2[n] ?= (n+1)*a2[0] (A_log = log(arange(1..16)) in the reference).
// If it holds, scans take the 1-transcendental geometric path.
// ---------------------------------------------------------------------------
__global__ void a2prep_k(const void* __restrict__ alog, float* __restrict__ a2fo,
                         int* flagp) {
  const int d = threadIdx.x;             // 384 threads, one d each
  const int f = flagp[0];
  float a2[16];
#pragma unroll
  for (int n = 0; n < 16; ++n) {
    const float v = f ? bf(((const __hip_bfloat16*)alog)[d * 16 + n])
                      : ((const float*)alog)[d * 16 + n];
    a2[n] = -1.4426950408889634f * __expf(v);
    a2fo[d * 16 + n] = a2[n];
  }
  int ok = 1;
#pragma unroll
  for (int n = 1; n < 16; ++n) {
    const float ref = (float)(n + 1) * a2[0];
    if (fabsf(a2[n] - ref) > 1e-3f * fabsf(ref)) ok = 0;
  }
  if (!ok) atomicAnd(&flagp[1], 0);
}

// ---------------------------------------------------------------------------
// perm normalizer: int64 storage has all odd int32 words zero (values<4096).
// ---------------------------------------------------------------------------
__global__ void perm_k(const int* p0, const int* p1, int* d0, int* d1) {
  __shared__ int s_or;
  const int* src = blockIdx.x ? p1 : p0;
  int*       dst = blockIdx.x ? d1 : d0;
  if (threadIdx.x == 0) s_or = 0;
  __syncthreads();
  int loc = 0;
  for (int i = threadIdx.x; i < 2048; i += 1024) loc |= src[2 * i + 1];
  atomicOr(&s_or, loc);
  __syncthreads();
  const bool is64 = (s_or == 0);
  for (int j = threadIdx.x; j < 4096; j += 1024)
    dst[j] = is64 ? (int)((const long long*)src)[j] : src[j];
}

// ---------------------------------------------------------------------------
// fused normalization of weight tensors to bf16 (one launch)
// ---------------------------------------------------------------------------
struct NormSet { const void* src[8]; void* dst[8]; int n[8]; };
__global__ void norm_all(NormSet s, const int* flagp) {
  const int idx = blockIdx.x * 256 + threadIdx.x;
  const int f = flagp[0];
#pragma unroll
  for (int t = 0; t < 8; ++t) {
    if (idx < s.n[t]) {
      __hip_bfloat16* d = (__hip_bfloat16*)s.dst[t];
      if (f) d[idx] = ((const __hip_bfloat16*)s.src[t])[idx];
      else   d[idx] = __float2bfloat16(((const float*)s.src[t])[idx]);
    }
  }
}

// ---------------------------------------------------------------------------
// Wcomb bf16 (512 x 384): rows 0..383 = dt_proj_w @ x_proj_w[0:24] (fused dt
// matrix), rows 384..415 = x_proj_w[24:56] (B then C), rows 416..511 = 0.
// ---------------------------------------------------------------------------
__global__ void prep_k(const __hip_bfloat16* __restrict__ dtw,
                       const __hip_bfloat16* __restrict__ xw,
                       __hip_bfloat16* __restrict__ wcomb) {
  const int idx = blockIdx.x * 256 + threadIdx.x;
  if (idx >= 512 * 384) return;
  const int n = idx / 384, k = idx - n * 384;
  float v = 0.f;
  if (n < 384) {
#pragma unroll
    for (int r = 0; r < 24; ++r) v += bf(dtw[n * 24 + r]) * bf(xw[r * 384 + k]);
  } else if (n < 416) {
    v = bf(xw[(24 + n - 384) * 384 + k]);
  }
  wcomb[idx] = __float2bfloat16(v);
}

// ---------------------------------------------------------------------------
// cvt_k: fused perm-gather + dtype-normalize of hidden_states into bf16 hsb.
// ---------------------------------------------------------------------------
__global__ void cvt_k(const void* __restrict__ hs, __hip_bfloat16* __restrict__ dst,
                      const int* __restrict__ gidx, const int* __restrict__ flagp) {
  const int idx = blockIdx.x * 256 + threadIdx.x;
  if (idx >= MTOT * 48) return;
  const int j = idx % 48;        // 8-elem group within row
  const int r = idx / 48;        // destination (reordered) token row
  const int b = r / L_, t = r - b * L_;
  const int src = b * L_ + (t == 0 ? 0 : 1 + gidx[t - 1]);
  uint4 o;
  if (flagp[0]) {
    o = *(const uint4*)((const __hip_bfloat16*)hs + (size_t)src * 384 + j * 8);
  } else {
    const float* f = (const float*)hs + (size_t)src * 384 + j * 8;
    const float4 f0 = *(const float4*)f;
    const float4 f1 = *(const float4*)(f + 4);
    o.x = f2bu(f0.x) | ((unsigned)f2bu(f0.y) << 16);
    o.y = f2bu(f0.z) | ((unsigned)f2bu(f0.w) << 16);
    o.z = f2bu(f1.x) | ((unsigned)f2bu(f1.y) << 16);
    o.w = f2bu(f1.z) | ((unsigned)f2bu(f1.w) << 16);
  }
  *(uint4*)(dst + (size_t)r * 384 + j * 8) = o;
}

// ---------------------------------------------------------------------------
// MFMA GEMM, m97 structure: 128x128 tile, K=384 = 12 x BK32, staging via
// global_load_lds w=16, single-buffered LDS, 2 barriers/K-step, 3 blocks/CU.
// Bijective XCD-contiguous tile remap (keeps A-panel on one XCD's L2).
// ---------------------------------------------------------------------------
template<int GATHER, int EPI>
__global__ __launch_bounds__(256, 3)
void gemm_k(const __hip_bfloat16* __restrict__ A, const __hip_bfloat16* __restrict__ W,
            void* __restrict__ e0, void* __restrict__ e1,
            const __hip_bfloat16* __restrict__ bias,
            const int* __restrict__ gidx, const int* __restrict__ flagp,
            int M, int N)
{
  __shared__ __align__(16) __hip_bfloat16 lA[128 * 32];
  __shared__ __align__(16) __hip_bfloat16 lB[128 * 32];
  const int tid  = threadIdx.x;
  const int lane = tid & 63;
  const int wv   = tid >> 6;
  const int wm   = wv >> 1, wn = wv & 1;
  const int lrow = lane & 15, quad = lane >> 4;
  const int fbf  = flagp[0];              // 1 = bf16 external storage

  const int NT = gridDim.x;
  const int nblocks = NT * (int)gridDim.y;
  const int id = blockIdx.y * NT + blockIdx.x;
  const int q8 = nblocks >> 3, r8 = nblocks & 7;
  const int xcd = id & 7, slot = id >> 3;
  const int nid = (xcd < r8 ? xcd * (q8 + 1)
                            : r8 * (q8 + 1) + (xcd - r8) * q8) + slot;
  const int mt = nid / NT, nt = nid - mt * NT;

  const __hip_bfloat16* aSrc[2];
  const __hip_bfloat16* bSrc[2];
  __hip_bfloat16* aDst[2];
  __hip_bfloat16* bDst[2];
#pragma unroll
  for (int p = 0; p < 2; ++p) {
    const int row = p * 64 + (tid >> 2);   // tile row 0..127
    const int kc  = (tid & 3) * 8;         // element offset in BK=32
    int r = mt * 128 + row;
    if (r >= M) r = M - 1;                 // tail tile: duplicate a valid row
    int src;
    if (GATHER) { const int b = r / L_, t = r - b * L_;
                  src = b * L_ + (t == 0 ? 0 : 1 + gidx[t - 1]); }
    else        { src = r; }
    aSrc[p] = A + (size_t)src * 384 + kc;
    const int c = nt * 128 + row;          // N is a multiple of 128 for all 3
    bSrc[p] = W + (size_t)c * 384 + kc;
    aDst[p] = &lA[(p * 256 + tid) * 8];
    bDst[p] = &lB[(p * 256 + tid) * 8];
  }

  f32x4 acc[4][4] = {};

#pragma unroll
  for (int kt = 0; kt < 12; ++kt) {        // K = 12 * 32
    __syncthreads();                       // WAR: prior ds_reads done
#pragma unroll
    for (int p = 0; p < 2; ++p) gld16(aSrc[p] + kt * 32, aDst[p]);
#pragma unroll
    for (int p = 0; p < 2; ++p) gld16(bSrc[p] + kt * 32, bDst[p]);
    __syncthreads();                       // staged data visible
    bf16x8 af[4], bfr[4];
#pragma unroll
    for (int i = 0; i < 4; ++i)
      af[i] = *reinterpret_cast<const bf16x8*>(&lA[(wm * 64 + i * 16 + lrow) * 32 + quad * 8]);
#pragma unroll
    for (int j = 0; j < 4; ++j)
      bfr[j] = *reinterpret_cast<const bf16x8*>(&lB[(wn * 64 + j * 16 + lrow) * 32 + quad * 8]);
#pragma unroll
    for (int i = 0; i < 4; ++i)
#pragma unroll
      for (int j = 0; j < 4; ++j)
        acc[i][j] = __builtin_amdgcn_mfma_f32_16x16x32_bf16(af[i], bfr[j], acc[i][j], 0, 0, 0);
  }

  // epilogue: D[reg] = C[row=(lane>>4)*4+reg][col=lane&15]  (m89-verified)
#pragma unroll
  for (int i = 0; i < 4; ++i) {
    const int row0 = mt * 128 + wm * 64 + i * 16 + quad * 4;
#pragma unroll
    for (int j = 0; j < 4; ++j) {
      const int col = nt * 128 + wn * 64 + j * 16 + lrow;
      if (col >= N) continue;
#pragma unroll
      for (int rg = 0; rg < 4; ++rg) {
        const int r = row0 + rg;
        if (r >= M) continue;
        const float v = acc[i][j][rg];
        if (EPI == 0) {          // in_proj: x half -> e0, z half -> e1 (bf16)
          if (col < 384) ((__hip_bfloat16*)e0)[(size_t)r * 384 + col] = __float2bfloat16(v);
          else           ((__hip_bfloat16*)e1)[(size_t)r * 384 + (col - 384)] = __float2bfloat16(v);
        } else if (EPI == 1) {   // dt: bias+softplus (bf16); B/C (fp32)
          if (col < 384) {
            const float x = v + bf(bias[col]);
            const float sp = (x > 20.f) ? x : log1pf(__expf(x));
            ((__hip_bfloat16*)e0)[(size_t)r * 384 + col] = __float2bfloat16(sp);
          } else if (col < 416) {
            ((float*)e1)[(size_t)r * 32 + (col - 384)] = v;
          }
        } else {                 // final out: dtype per runtime flag
          if (fbf) ((__hip_bfloat16*)e0)[(size_t)r * 384 + col] = __float2bfloat16(v);
          else     ((float*)e0)[(size_t)r * 384 + col] = v;
        }
      }
    }
  }
}

// ---------------------------------------------------------------------------
// depthwise conv k=4 (taps t-1..t+2) + silu on x half; 8 channels/thread.
// ---------------------------------------------------------------------------
__global__ void convx_k(const __hip_bfloat16* __restrict__ xh,
                        const __hip_bfloat16* __restrict__ cxw,
                        __hip_bfloat16* __restrict__ xc) {
  const int idx = blockIdx.x * 256 + threadIdx.x;
  if (idx >= MTOT * 48) return;
  const int g  = idx % 48;       // channel group (8 ch)
  const int rg = idx / 48;       // token row
  const int t  = rg % L_;
  const int c0 = g * 8;
  uint4 wv[4];                   // weights: channels c0..c0+7 x 4 taps
#pragma unroll
  for (int p = 0; p < 4; ++p) wv[p] = *(const uint4*)(cxw + c0 * 4 + p * 8);
  float acc[8] = {};
#pragma unroll
  for (int k = 0; k < 4; ++k) {
    const int tt = t + k - 1;
    if (tt < 0 || tt >= L_) continue;
    const uint4 u = *(const uint4*)(xh + (size_t)(rg + k - 1) * 384 + c0);
#pragma unroll
    for (int j = 0; j < 8; ++j) {
      const int e = j * 4 + k;                      // weight flat element
      acc[j] += u16f(wv[e >> 3], e & 7) * u16f(u, j);
    }
  }
  uint4 o;
#pragma unroll
  for (int p = 0; p < 4; ++p) {
    const float s0 = acc[2 * p]     / (1.f + __expf(-acc[2 * p]));
    const float s1 = acc[2 * p + 1] / (1.f + __expf(-acc[2 * p + 1]));
    (&o.x)[p] = f2bu(s0) | ((unsigned)f2bu(s1) << 16);
  }
  *(uint4*)(xc + (size_t)rg * 384 + c0) = o;
}

// ---------------------------------------------------------------------------
// scan phase 1: per (b, chunk, d) local scan with h0=0. Geometric-A fast
// path (flag[1]): dA[n] = e1^(n+1), ONE exp2 per timestep + log-depth power
// tree, vs 16 exp2 (round-10: scans were transcendental-issue-bound,
// VALUBusy 64%, 16x v_exp_f32 per (t,d)). B/C via ds_read_b128.
// ---------------------------------------------------------------------------
__global__ __launch_bounds__(128)
void scan1_k(const __hip_bfloat16* __restrict__ dt, const float* __restrict__ bc,
             __hip_bfloat16* xcio,
             const float* __restrict__ a2f,
             const __hip_bfloat16* __restrict__ dpar,
             float* __restrict__ pbuf, float* __restrict__ hend,
             const int* __restrict__ flagp)
{
  __shared__ __align__(16) float lBC[CH * 32];
  const int blk = blockIdx.x;
  const int dt3 = blk % 3;
  const int c   = (blk / 3) % NCH;
  const int b   = blk / (3 * NCH);
  const int d   = dt3 * 128 + threadIdx.x;
  const int t0  = c * CH;
  const int r0  = b * L_ + t0;
  const int tmax = (L_ - t0 < CH) ? (L_ - t0) : CH;
  for (int i = threadIdx.x; i < tmax * 32; i += 128) lBC[i] = bc[(size_t)r0 * 32 + i];
  __syncthreads();

  float h[16];
#pragma unroll
  for (int n = 0; n < 16; ++n) h[n] = 0.f;
  float sdt = 0.f;
  const float Dd = bf(dpar[d]);
  const size_t base = ((size_t)(c * 8 + b) * 16) * 384 + d;

  if (flagp[1]) {                          // geometric A: a2[n] = (n+1)*a2b
    const float a2b = a2f[d * 16];
    for (int tt = 0; tt < tmax; ++tt) {
      const size_t r = (size_t)(r0 + tt);
      const float dtv = bf(dt[r * 384 + d]);
      const float xv  = bf(xcio[r * 384 + d]);
      sdt += dtv;
      const float dtx = dtv * xv;
      float pw[17];
      pw[1] = exp2f(dtv * a2b);
#pragma unroll
      for (int n = 2; n <= 16; ++n) pw[n] = pw[n >> 1] * pw[n - (n >> 1)];
      float4 bq[4], cq[4];
#pragma unroll
      for (int q = 0; q < 4; ++q) {
        bq[q] = *(const float4*)&lBC[tt * 32 + q * 4];
        cq[q] = *(const float4*)&lBC[tt * 32 + 16 + q * 4];
      }
      float y = 0.f;
#pragma unroll
      for (int n = 0; n < 16; ++n) {
        h[n] = h[n] * pw[n + 1] + dtx * (&bq[n >> 2].x)[n & 3];
        y += h[n] * (&cq[n >> 2].x)[n & 3];
      }
      y += Dd * xv;
      xcio[r * 384 + d] = __float2bfloat16(y);
    }
    float Ep[17];
    Ep[1] = exp2f(sdt * a2b);
#pragma unroll
    for (int n = 2; n <= 16; ++n) Ep[n] = Ep[n >> 1] * Ep[n - (n >> 1)];
#pragma unroll
    for (int n = 0; n < 16; ++n) {
      pbuf[base + n * 384] = Ep[n + 1];
      hend[base + n * 384] = h[n];
    }
  } else {                                 // generic A fallback
    float a2[16];
#pragma unroll
    for (int n = 0; n < 16; ++n) a2[n] = a2f[d * 16 + n];
    for (int tt = 0; tt < tmax; ++tt) {
      const size_t r = (size_t)(r0 + tt);
      const float dtv = bf(dt[r * 384 + d]);
      const float xv  = bf(xcio[r * 384 + d]);
      sdt += dtv;
      const float dtx = dtv * xv;
      float4 bq[4], cq[4];
#pragma unroll
      for (int q = 0; q < 4; ++q) {
        bq[q] = *(const float4*)&lBC[tt * 32 + q * 4];
        cq[q] = *(const float4*)&lBC[tt * 32 + 16 + q * 4];
      }
      float y = 0.f;
#pragma unroll
      for (int n = 0; n < 16; ++n) {
        h[n] = h[n] * exp2f(dtv * a2[n]) + dtx * (&bq[n >> 2].x)[n & 3];
        y += h[n] * (&cq[n >> 2].x)[n & 3];
      }
      y += Dd * xv;
      xcio[r * 384 + d] = __float2bfloat16(y);
    }
#pragma unroll
    for (int n = 0; n < 16; ++n) {
      pbuf[base + n * 384] = exp2f(sdt * a2[n]);
      hend[base + n * 384] = h[n];
    }
  }
}

// ---------------------------------------------------------------------------
// scan phase 2: cross-chunk scan per (b,d,n); rewrites pbuf with h_start
// ---------------------------------------------------------------------------
__global__ void scan2_k(float* __restrict__ pbuf, const float* __restrict__ hend) {
  const int tid = blockIdx.x * 256 + threadIdx.x;   // 49152 total
  const int d = tid % 384;
  const int n = (tid / 384) & 15;
  const int b = tid / 6144;
  float H = 0.f;
  for (int c = 0; c < NCH; ++c) {
    const size_t idx = ((size_t)(c * 8 + b) * 16 + n) * 384 + d;
    const float p = pbuf[idx];
    const float he = hend[idx];
    pbuf[idx] = H;
    H = p * H + he;
  }
}

// ---------------------------------------------------------------------------
// scan phase 3 (light): y(t) = y_local(t) + sum_n C(t,n)*W^(n+1)*h_start[n]
// with W = exp2(sdt*a2b) on the geometric path; fused z-conv + silu gate.
// ---------------------------------------------------------------------------
__global__ __launch_bounds__(128)
void scan3_k(__hip_bfloat16* dtyg, const float* __restrict__ bc,
             const __hip_bfloat16* __restrict__ yl,
             const __hip_bfloat16* __restrict__ zh,
             const __hip_bfloat16* __restrict__ czw,
             const float* __restrict__ a2f,
             const float* __restrict__ hstart,
             const int* __restrict__ flagp)
{
  __shared__ __align__(16) float lC[CH * 16];
  const int blk = blockIdx.x;
  const int dt3 = blk % 3;
  const int c   = (blk / 3) % NCH;
  const int b   = blk / (3 * NCH);
  const int d   = dt3 * 128 + threadIdx.x;
  const int t0  = c * CH;
  const int r0  = b * L_ + t0;
  const int tmax = (L_ - t0 < CH) ? (L_ - t0) : CH;
  for (int i = threadIdx.x; i < tmax * 16; i += 128)
    lC[i] = bc[(size_t)r0 * 32 + (i >> 4) * 32 + 16 + (i & 15)];
  __syncthreads();

  float hs_[16];
  const size_t base = ((size_t)(c * 8 + b) * 16) * 384 + d;
#pragma unroll
  for (int n = 0; n < 16; ++n) hs_[n] = hstart[base + n * 384];
  float cw[4];
#pragma unroll
  for (int k = 0; k < 4; ++k) cw[k] = bf(czw[d * 4 + k]);

  float zm1 = (t0 - 1 >= 0) ? bf(zh[(size_t)(r0 - 1) * 384 + d]) : 0.f;
  float z0  = bf(zh[(size_t)r0 * 384 + d]);
  float zp1 = (t0 + 1 < L_) ? bf(zh[(size_t)(r0 + 1) * 384 + d]) : 0.f;
  float sdt = 0.f;

  if (flagp[1]) {                          // geometric A fast path
    const float a2b = a2f[d * 16];
    for (int tt = 0; tt < tmax; ++tt) {
      const int t = t0 + tt;
      const size_t r = (size_t)(r0 + tt);
      const float zp2 = (t + 2 < L_) ? bf(zh[(r + 2) * 384 + d]) : 0.f;
      const float dtv = bf(dtyg[r * 384 + d]);
      sdt += dtv;
      float pw[17];
      pw[1] = exp2f(sdt * a2b);
#pragma unroll
      for (int n = 2; n <= 16; ++n) pw[n] = pw[n >> 1] * pw[n - (n >> 1)];
      float4 cq[4];
#pragma unroll
      for (int q = 0; q < 4; ++q) cq[q] = *(const float4*)&lC[tt * 16 + q * 4];
      float corr = 0.f;
#pragma unroll
      for (int n = 0; n < 16; ++n)
        corr += (&cq[n >> 2].x)[n & 3] * hs_[n] * pw[n + 1];
      const float y = bf(yl[r * 384 + d]) + corr;
      const float zc = cw[0] * zm1 + cw[1] * z0 + cw[2] * zp1 + cw[3] * zp2;
      const float zs = zc / (1.f + __expf(-zc));
      dtyg[r * 384 + d] = __float2bfloat16(y * zs);
      zm1 = z0; z0 = zp1; zp1 = zp2;
    }
  } else {                                 // generic A fallback
    float a2[16];
#pragma unroll
    for (int n = 0; n < 16; ++n) a2[n] = a2f[d * 16 + n];
    for (int tt = 0; tt < tmax; ++tt) {
      const int t = t0 + tt;
      const size_t r = (size_t)(r0 + tt);
      const float zp2 = (t + 2 < L_) ? bf(zh[(r + 2) * 384 + d]) : 0.f;
      const float dtv = bf(dtyg[r * 384 + d]);
      sdt += dtv;
      float4 cq[4];
#pragma unroll
      for (int q = 0; q < 4; ++q) cq[q] = *(const float4*)&lC[tt * 16 + q * 4];
      float corr = 0.f;
#pragma unroll
      for (int n = 0; n < 16; ++n)
        corr += (&cq[n >> 2].x)[n & 3] * hs_[n] * exp2f(sdt * a2[n]);
      const float y = bf(yl[r * 384 + d]) + corr;
      const float zc = cw[0] * zm1 + cw[1] * z0 + cw[2] * zp1 + cw[3] * zp2;
      const float zs = zc / (1.f + __expf(-zc));
      dtyg[r * 384 + d] = __float2bfloat16(y * zs);
      zm1 = z0; z0 = zp1; zp1 = zp2;
    }
  }
}

// ---------------------------------------------------------------------------
extern "C" void kernel_launch(void* const* d_in, const int* in_sizes, int n_in,
                              void* d_out, int out_size, void* d_ws, size_t ws_size,
                              hipStream_t stream) {
  const void* hs   = d_in[0];
  const void* w_in = d_in[1];
  const void* cxw  = d_in[2];
  const void* czw  = d_in[3];
  const void* xw   = d_in[4];
  const void* dtw  = d_in[5];
  const void* dtb  = d_in[6];
  const void* alog = d_in[7];
  const void* dpar = d_in[8];
  const void* ow   = d_in[9];
  const int* perm  = (const int*)d_in[10];
  const int* permr = (const int*)d_in[11];

  char* ws = (char*)d_ws;
  size_t off = 0;
  auto alloc = [&](size_t nbytes) -> char* {
    char* p = ws + off;
    off += (nbytes + 255) & ~(size_t)255;
    return p;
  };
  int* flag              = (int*)alloc(256);
  int* nperm             = (int*)alloc(4096 * 4);
  int* npermr            = (int*)alloc(4096 * 4);
  float* a2f             = (float*)alloc(6144 * 4);
  __hip_bfloat16* w_inb  = (__hip_bfloat16*)alloc(294912 * 2);
  __hip_bfloat16* cxwb   = (__hip_bfloat16*)alloc(1536 * 2);
  __hip_bfloat16* czwb   = (__hip_bfloat16*)alloc(1536 * 2);
  __hip_bfloat16* xwb    = (__hip_bfloat16*)alloc(21504 * 2);
  __hip_bfloat16* dtwb   = (__hip_bfloat16*)alloc(9216 * 2);
  __hip_bfloat16* dtbb   = (__hip_bfloat16*)alloc(384 * 2);
  __hip_bfloat16* dparb  = (__hip_bfloat16*)alloc(384 * 2);
  __hip_bfloat16* owb    = (__hip_bfloat16*)alloc(147456 * 2);
  __hip_bfloat16* wcombb = (__hip_bfloat16*)alloc((size_t)512 * 384 * 2);
  __hip_bfloat16* hsb    = (__hip_bfloat16*)alloc((size_t)MTOT * 384 * 2);  // 25.2 MB
  __hip_bfloat16* zh     = (__hip_bfloat16*)alloc((size_t)MTOT * 384 * 2);  // 25.2 MB
  __hip_bfloat16* xc     = (__hip_bfloat16*)alloc((size_t)MTOT * 384 * 2);  // 25.2 MB
  __hip_bfloat16* dtyg   = (__hip_bfloat16*)alloc((size_t)MTOT * 384 * 2);  // 25.2 MB
  float*          bcf    = (float*)alloc((size_t)MTOT * 32 * 4);            // 4.2 MB
  // d_out as scratch: xh (bf16, dies at convx), then pbuf+hend (33.8 MB of 50.3)
  __hip_bfloat16* xh   = (__hip_bfloat16*)d_out;
  float*          pbuf = (float*)d_out;
  float*          hend = (float*)((char*)d_out + (size_t)NCH * B_ * NS * DH * 4);

  // 0) dtype + perm + A-structure normalization
  flag_k<<<1, 64, 0, stream>>>(hs, flag);
  perm_k<<<2, 1024, 0, stream>>>(perm, permr, nperm, npermr);
  a2prep_k<<<1, 384, 0, stream>>>(alog, a2f, flag);
  NormSet ns;
  ns.src[0] = w_in; ns.dst[0] = w_inb; ns.n[0] = 294912;
  ns.src[1] = ow;   ns.dst[1] = owb;   ns.n[1] = 147456;
  ns.src[2] = xw;   ns.dst[2] = xwb;   ns.n[2] = 21504;
  ns.src[3] = dtw;  ns.dst[3] = dtwb;  ns.n[3] = 9216;
  ns.src[4] = cxw;  ns.dst[4] = cxwb;  ns.n[4] = 1536;
  ns.src[5] = czw;  ns.dst[5] = czwb;  ns.n[5] = 1536;
  ns.src[6] = dtb;  ns.dst[6] = dtbb;  ns.n[6] = 384;
  ns.src[7] = dpar; ns.dst[7] = dparb; ns.n[7] = 384;
  norm_all<<<1152, 256, 0, stream>>>(ns, flag);
  // 1) fused dt/BC weight build
  prep_k<<<768, 256, 0, stream>>>(dtwb, xwb, wcombb);
  // 2) fused perm-gather + bf16 convert of hidden_states
  cvt_k<<<(MTOT * 48 + 255) / 256, 256, 0, stream>>>(hs, hsb, nperm, flag);
  // 3) in_proj MFMA GEMM (m97 structure) -> xh (d_out), zh
  gemm_k<0, 0><<<dim3(6, 257), 256, 0, stream>>>(
      hsb, w_inb, xh, zh, nullptr, nullptr, flag, MTOT, 768);
  // 4) depthwise conv + silu on x half (8 ch/thread)
  convx_k<<<(MTOT * 48 + 255) / 256, 256, 0, stream>>>(xh, cxwb, xc);
  // 5) fused dt (bias+softplus, bf16) and B/C (fp32) MFMA GEMM
  gemm_k<0, 1><<<dim3(4, 257), 256, 0, stream>>>(
      xc, wcombb, dtyg, bcf, dtbb, nullptr, flag, MTOT, 512);
  // 6) chunked selective scan (y_local in phase 1; light correction phase 3)
  scan1_k<<<B_ * NCH * 3, 128, 0, stream>>>(dtyg, bcf, xc, a2f, dparb, pbuf, hend, flag);
  scan2_k<<<192, 256, 0, stream>>>(pbuf, hend);
  scan3_k<<<B_ * NCH * 3, 128, 0, stream>>>(dtyg, bcf, xc, zh, czwb, a2f, pbuf, flag);
  // 7) out_proj MFMA GEMM with inverse-perm gather -> final output
  gemm_k<1, 2><<<dim3(3, 257), 256, 0, stream>>>(
      dtyg, owb, d_out, nullptr, nullptr, npermr, flag, MTOT, 384);
  (void)in_sizes; (void)n_in; (void)out_size; (void)ws_size;
}

// Round 4
// 384.525 us; speedup vs baseline: 1.6520x; 1.1006x over previous
//
#include <hip/hip_runtime.h>
#include <hip/hip_bf16.h>

#define DEVI __device__ __forceinline__

constexpr int B_   = 8;
constexpr int L_   = 4097;
constexpr int MTOT = B_ * L_;          // 32776 tokens
constexpr int DH   = 384;              // d_half
constexpr int NS   = 16;               // d_state
constexpr int CH   = 48;               // scan chunk length
constexpr int NCH  = (L_ + CH - 1) / CH;  // 86 chunks

typedef __bf16 bf16x8 __attribute__((ext_vector_type(8)));
typedef float  f32x4  __attribute__((ext_vector_type(4)));

DEVI float bl(unsigned v) { return __uint_as_float(v << 16); }          // low bf16
DEVI float bh(unsigned v) { return __uint_as_float(v & 0xffff0000u); }  // high bf16
DEVI float bf(const __hip_bfloat16 x) { return __bfloat162float(x); }
DEVI unsigned short f2bu(float x) {
  __hip_bfloat16 b = __float2bfloat16(x);
  return *(unsigned short*)&b;
}
DEVI float u16f(const uint4& u, int j) {   // element j (0..7) of 8 packed bf16
  const unsigned w = (&u.x)[j >> 1];
  return (j & 1) ? bh(w) : bl(w);
}
// fast softplus: 2 HW transcendentals vs log1pf's ~30-instr libm sequence
// (round-12: dt-GEMM epilogue was VALU-bound on log1pf, VALUBusy 46%).
// error ~2 ulp fp32, far below the bf16 storage rounding of dt.
DEVI float softplus_f(float x) {
  return (x > 20.f) ? x : __logf(1.f + __expf(x));
}

// global -> LDS direct (16B per lane). LDS dest must be wave-uniform + lane*16.
DEVI void gld16(const __hip_bfloat16* g, __hip_bfloat16* l) {
  __builtin_amdgcn_global_load_lds(
      (const __attribute__((address_space(1))) void*)g,
      (__attribute__((address_space(3))) void*)l, 16, 0, 0);
}

// ---------------------------------------------------------------------------
// dtype detector: hidden_states ~ N(0,1). bf16 -> every even u16 has exponent
// field ~126; fp32 -> even u16 are mantissa bits (uniform). flag=1 -> bf16.
// flag[1] = geometric-A structure flag (init 1, cleared by a2prep_k).
// ---------------------------------------------------------------------------
__global__ void flag_k(const void* hs, int* flagp) {
  if (threadIdx.x == 0 && blockIdx.x == 0) {
    const unsigned short* u = (const unsigned short*)hs;
    int ok = 1;
    for (int i = 0; i < 8; ++i) {
      const unsigned short v = u[2 * i];
      const int e = (v >> 7) & 0xFF;
      if (!(v == 0 || (e >= 100 && e <= 140))) ok = 0;
    }
    flagp[0] = ok;
    flagp[1] = 1;
  }
}

// ---------------------------------------------------------------------------
// a2prep_k: a2[d][n] = -log2(e)*exp(A_log[d][n]) in fp32, plus structure
// check a2[n] ?= (n+1)*a2[0] (A_log = log(arange(1..16)) in the reference).
// If it holds, scans take the 1-transcendental geometric path.
// ---------------------------------------------------------------------------
__global__ void a2prep_k(const void* __restrict__ alog, float* __restrict__ a2fo,
                         int* flagp) {
  const int d = threadIdx.x;             // 384 threads, one d each
  const int f = flagp[0];
  float a2[16];
#pragma unroll
  for (int n = 0; n < 16; ++n) {
    const float v = f ? bf(((const __hip_bfloat16*)alog)[d * 16 + n])
                      : ((const float*)alog)[d * 16 + n];
    a2[n] = -1.4426950408889634f * __expf(v);
    a2fo[d * 16 + n] = a2[n];
  }
  int ok = 1;
#pragma unroll
  for (int n = 1; n < 16; ++n) {
    const float ref = (float)(n + 1) * a2[0];
    if (fabsf(a2[n] - ref) > 1e-3f * fabsf(ref)) ok = 0;
  }
  if (!ok) atomicAnd(&flagp[1], 0);
}

// ---------------------------------------------------------------------------
// perm normalizer: int64 storage has all odd int32 words zero (values<4096).
// ---------------------------------------------------------------------------
__global__ void perm_k(const int* p0, const int* p1, int* d0, int* d1) {
  __shared__ int s_or;
  const int* src = blockIdx.x ? p1 : p0;
  int*       dst = blockIdx.x ? d1 : d0;
  if (threadIdx.x == 0) s_or = 0;
  __syncthreads();
  int loc = 0;
  for (int i = threadIdx.x; i < 2048; i += 1024) loc |= src[2 * i + 1];
  atomicOr(&s_or, loc);
  __syncthreads();
  const bool is64 = (s_or == 0);
  for (int j = threadIdx.x; j < 4096; j += 1024)
    dst[j] = is64 ? (int)((const long long*)src)[j] : src[j];
}

// ---------------------------------------------------------------------------
// fused normalization of weight tensors to bf16 (one launch)
// ---------------------------------------------------------------------------
struct NormSet { const void* src[8]; void* dst[8]; int n[8]; };
__global__ void norm_all(NormSet s, const int* flagp) {
  const int idx = blockIdx.x * 256 + threadIdx.x;
  const int f = flagp[0];
#pragma unroll
  for (int t = 0; t < 8; ++t) {
    if (idx < s.n[t]) {
      __hip_bfloat16* d = (__hip_bfloat16*)s.dst[t];
      if (f) d[idx] = ((const __hip_bfloat16*)s.src[t])[idx];
      else   d[idx] = __float2bfloat16(((const float*)s.src[t])[idx]);
    }
  }
}

// ---------------------------------------------------------------------------
// Wcomb bf16 (512 x 384): rows 0..383 = dt_proj_w @ x_proj_w[0:24] (fused dt
// matrix), rows 384..415 = x_proj_w[24:56] (B then C), rows 416..511 = 0.
// ---------------------------------------------------------------------------
__global__ void prep_k(const __hip_bfloat16* __restrict__ dtw,
                       const __hip_bfloat16* __restrict__ xw,
                       __hip_bfloat16* __restrict__ wcomb) {
  const int idx = blockIdx.x * 256 + threadIdx.x;
  if (idx >= 512 * 384) return;
  const int n = idx / 384, k = idx - n * 384;
  float v = 0.f;
  if (n < 384) {
#pragma unroll
    for (int r = 0; r < 24; ++r) v += bf(dtw[n * 24 + r]) * bf(xw[r * 384 + k]);
  } else if (n < 416) {
    v = bf(xw[(24 + n - 384) * 384 + k]);
  }
  wcomb[idx] = __float2bfloat16(v);
}

// ---------------------------------------------------------------------------
// cvt_k: fused perm-gather + dtype-normalize of hidden_states into bf16 hsb.
// ---------------------------------------------------------------------------
__global__ void cvt_k(const void* __restrict__ hs, __hip_bfloat16* __restrict__ dst,
                      const int* __restrict__ gidx, const int* __restrict__ flagp) {
  const int idx = blockIdx.x * 256 + threadIdx.x;
  if (idx >= MTOT * 48) return;
  const int j = idx % 48;        // 8-elem group within row
  const int r = idx / 48;        // destination (reordered) token row
  const int b = r / L_, t = r - b * L_;
  const int src = b * L_ + (t == 0 ? 0 : 1 + gidx[t - 1]);
  uint4 o;
  if (flagp[0]) {
    o = *(const uint4*)((const __hip_bfloat16*)hs + (size_t)src * 384 + j * 8);
  } else {
    const float* f = (const float*)hs + (size_t)src * 384 + j * 8;
    const float4 f0 = *(const float4*)f;
    const float4 f1 = *(const float4*)(f + 4);
    o.x = f2bu(f0.x) | ((unsigned)f2bu(f0.y) << 16);
    o.y = f2bu(f0.z) | ((unsigned)f2bu(f0.w) << 16);
    o.z = f2bu(f1.x) | ((unsigned)f2bu(f1.y) << 16);
    o.w = f2bu(f1.z) | ((unsigned)f2bu(f1.w) << 16);
  }
  *(uint4*)(dst + (size_t)r * 384 + j * 8) = o;
}

// ---------------------------------------------------------------------------
// MFMA GEMM, m97 structure: 128x128 tile, K=384 = 12 x BK32, staging via
// global_load_lds w=16, single-buffered LDS, 2 barriers/K-step, 3 blocks/CU.
// Bijective XCD-contiguous tile remap (keeps A-panel on one XCD's L2).
// EPI=1 epilogue: fast softplus (round-12: log1pf was 46% VALUBusy); waves
// whose entire col range is the Wcomb zero-pad (cols>=416) skip MFMA.
// ---------------------------------------------------------------------------
template<int GATHER, int EPI>
__global__ __launch_bounds__(256, 3)
void gemm_k(const __hip_bfloat16* __restrict__ A, const __hip_bfloat16* __restrict__ W,
            void* __restrict__ e0, void* __restrict__ e1,
            const __hip_bfloat16* __restrict__ bias,
            const int* __restrict__ gidx, const int* __restrict__ flagp,
            int M, int N)
{
  __shared__ __align__(16) __hip_bfloat16 lA[128 * 32];
  __shared__ __align__(16) __hip_bfloat16 lB[128 * 32];
  const int tid  = threadIdx.x;
  const int lane = tid & 63;
  const int wv   = tid >> 6;
  const int wm   = wv >> 1, wn = wv & 1;
  const int lrow = lane & 15, quad = lane >> 4;
  const int fbf  = flagp[0];              // 1 = bf16 external storage

  const int NT = gridDim.x;
  const int nblocks = NT * (int)gridDim.y;
  const int id = blockIdx.y * NT + blockIdx.x;
  const int q8 = nblocks >> 3, r8 = nblocks & 7;
  const int xcd = id & 7, slot = id >> 3;
  const int nid = (xcd < r8 ? xcd * (q8 + 1)
                            : r8 * (q8 + 1) + (xcd - r8) * q8) + slot;
  const int mt = nid / NT, nt = nid - mt * NT;

  // wave whose whole 64-col band is Wcomb zero-pad: skip fragment+MFMA work
  const bool live = !(EPI == 1 && nt * 128 + wn * 64 >= 416);

  const __hip_bfloat16* aSrc[2];
  const __hip_bfloat16* bSrc[2];
  __hip_bfloat16* aDst[2];
  __hip_bfloat16* bDst[2];
#pragma unroll
  for (int p = 0; p < 2; ++p) {
    const int row = p * 64 + (tid >> 2);   // tile row 0..127
    const int kc  = (tid & 3) * 8;         // element offset in BK=32
    int r = mt * 128 + row;
    if (r >= M) r = M - 1;                 // tail tile: duplicate a valid row
    int src;
    if (GATHER) { const int b = r / L_, t = r - b * L_;
                  src = b * L_ + (t == 0 ? 0 : 1 + gidx[t - 1]); }
    else        { src = r; }
    aSrc[p] = A + (size_t)src * 384 + kc;
    const int c = nt * 128 + row;          // N is a multiple of 128 for all 3
    bSrc[p] = W + (size_t)c * 384 + kc;
    aDst[p] = &lA[(p * 256 + tid) * 8];
    bDst[p] = &lB[(p * 256 + tid) * 8];
  }

  f32x4 acc[4][4] = {};

#pragma unroll
  for (int kt = 0; kt < 12; ++kt) {        // K = 12 * 32
    __syncthreads();                       // WAR: prior ds_reads done
#pragma unroll
    for (int p = 0; p < 2; ++p) gld16(aSrc[p] + kt * 32, aDst[p]);
#pragma unroll
    for (int p = 0; p < 2; ++p) gld16(bSrc[p] + kt * 32, bDst[p]);
    __syncthreads();                       // staged data visible
    if (live) {
      bf16x8 af[4], bfr[4];
#pragma unroll
      for (int i = 0; i < 4; ++i)
        af[i] = *reinterpret_cast<const bf16x8*>(&lA[(wm * 64 + i * 16 + lrow) * 32 + quad * 8]);
#pragma unroll
      for (int j = 0; j < 4; ++j)
        bfr[j] = *reinterpret_cast<const bf16x8*>(&lB[(wn * 64 + j * 16 + lrow) * 32 + quad * 8]);
#pragma unroll
      for (int i = 0; i < 4; ++i)
#pragma unroll
        for (int j = 0; j < 4; ++j)
          acc[i][j] = __builtin_amdgcn_mfma_f32_16x16x32_bf16(af[i], bfr[j], acc[i][j], 0, 0, 0);
    }
  }

  // epilogue: D[reg] = C[row=(lane>>4)*4+reg][col=lane&15]  (m89-verified)
#pragma unroll
  for (int i = 0; i < 4; ++i) {
    const int row0 = mt * 128 + wm * 64 + i * 16 + quad * 4;
#pragma unroll
    for (int j = 0; j < 4; ++j) {
      const int col = nt * 128 + wn * 64 + j * 16 + lrow;
      if (col >= N) continue;
#pragma unroll
      for (int rg = 0; rg < 4; ++rg) {
        const int r = row0 + rg;
        if (r >= M) continue;
        const float v = acc[i][j][rg];
        if (EPI == 0) {          // in_proj: x half -> e0, z half -> e1 (bf16)
          if (col < 384) ((__hip_bfloat16*)e0)[(size_t)r * 384 + col] = __float2bfloat16(v);
          else           ((__hip_bfloat16*)e1)[(size_t)r * 384 + (col - 384)] = __float2bfloat16(v);
        } else if (EPI == 1) {   // dt: bias+fast-softplus (bf16); B/C (fp32)
          if (col < 384) {
            const float sp = softplus_f(v + bf(bias[col]));
            ((__hip_bfloat16*)e0)[(size_t)r * 384 + col] = __float2bfloat16(sp);
          } else if (col < 416) {
            ((float*)e1)[(size_t)r * 32 + (col - 384)] = v;
          }
        } else {                 // final out: dtype per runtime flag
          if (fbf) ((__hip_bfloat16*)e0)[(size_t)r * 384 + col] = __float2bfloat16(v);
          else     ((float*)e0)[(size_t)r * 384 + col] = v;
        }
      }
    }
  }
}

// ---------------------------------------------------------------------------
// depthwise conv k=4 (taps t-1..t+2) + silu on x half; 8 channels/thread.
// ---------------------------------------------------------------------------
__global__ void convx_k(const __hip_bfloat16* __restrict__ xh,
                        const __hip_bfloat16* __restrict__ cxw,
                        __hip_bfloat16* __restrict__ xc) {
  const int idx = blockIdx.x * 256 + threadIdx.x;
  if (idx >= MTOT * 48) return;
  const int g  = idx % 48;       // channel group (8 ch)
  const int rg = idx / 48;       // token row
  const int t  = rg % L_;
  const int c0 = g * 8;
  uint4 wv[4];                   // weights: channels c0..c0+7 x 4 taps
#pragma unroll
  for (int p = 0; p < 4; ++p) wv[p] = *(const uint4*)(cxw + c0 * 4 + p * 8);
  float acc[8] = {};
#pragma unroll
  for (int k = 0; k < 4; ++k) {
    const int tt = t + k - 1;
    if (tt < 0 || tt >= L_) continue;
    const uint4 u = *(const uint4*)(xh + (size_t)(rg + k - 1) * 384 + c0);
#pragma unroll
    for (int j = 0; j < 8; ++j) {
      const int e = j * 4 + k;                      // weight flat element
      acc[j] += u16f(wv[e >> 3], e & 7) * u16f(u, j);
    }
  }
  uint4 o;
#pragma unroll
  for (int p = 0; p < 4; ++p) {
    const float s0 = acc[2 * p]     / (1.f + __expf(-acc[2 * p]));
    const float s1 = acc[2 * p + 1] / (1.f + __expf(-acc[2 * p + 1]));
    (&o.x)[p] = f2bu(s0) | ((unsigned)f2bu(s1) << 16);
  }
  *(uint4*)(xc + (size_t)rg * 384 + c0) = o;
}

// ---------------------------------------------------------------------------
// scan phase 1: per (b, chunk, d) local scan with h0=0. Geometric-A fast
// path (flag[1]): dA[n] = e1^(n+1), ONE exp2 per timestep + log-depth power
// tree. y_local written IN PLACE over xc; chunk decay P and h_end emitted.
// ---------------------------------------------------------------------------
__global__ __launch_bounds__(128)
void scan1_k(const __hip_bfloat16* __restrict__ dt, const float* __restrict__ bc,
             __hip_bfloat16* xcio,
             const float* __restrict__ a2f,
             const __hip_bfloat16* __restrict__ dpar,
             float* __restrict__ pbuf, float* __restrict__ hend,
             const int* __restrict__ flagp)
{
  __shared__ __align__(16) float lBC[CH * 32];
  const int blk = blockIdx.x;
  const int dt3 = blk % 3;
  const int c   = (blk / 3) % NCH;
  const int b   = blk / (3 * NCH);
  const int d   = dt3 * 128 + threadIdx.x;
  const int t0  = c * CH;
  const int r0  = b * L_ + t0;
  const int tmax = (L_ - t0 < CH) ? (L_ - t0) : CH;
  for (int i = threadIdx.x; i < tmax * 32; i += 128) lBC[i] = bc[(size_t)r0 * 32 + i];
  __syncthreads();

  float h[16];
#pragma unroll
  for (int n = 0; n < 16; ++n) h[n] = 0.f;
  float sdt = 0.f;
  const float Dd = bf(dpar[d]);
  const size_t base = ((size_t)(c * 8 + b) * 16) * 384 + d;

  if (flagp[1]) {                          // geometric A: a2[n] = (n+1)*a2b
    const float a2b = a2f[d * 16];
    for (int tt = 0; tt < tmax; ++tt) {
      const size_t r = (size_t)(r0 + tt);
      const float dtv = bf(dt[r * 384 + d]);
      const float xv  = bf(xcio[r * 384 + d]);
      sdt += dtv;
      const float dtx = dtv * xv;
      float pw[17];
      pw[1] = exp2f(dtv * a2b);
#pragma unroll
      for (int n = 2; n <= 16; ++n) pw[n] = pw[n >> 1] * pw[n - (n >> 1)];
      float4 bq[4], cq[4];
#pragma unroll
      for (int q = 0; q < 4; ++q) {
        bq[q] = *(const float4*)&lBC[tt * 32 + q * 4];
        cq[q] = *(const float4*)&lBC[tt * 32 + 16 + q * 4];
      }
      float y = 0.f;
#pragma unroll
      for (int n = 0; n < 16; ++n) {
        h[n] = h[n] * pw[n + 1] + dtx * (&bq[n >> 2].x)[n & 3];
        y += h[n] * (&cq[n >> 2].x)[n & 3];
      }
      y += Dd * xv;
      xcio[r * 384 + d] = __float2bfloat16(y);
    }
    float Ep[17];
    Ep[1] = exp2f(sdt * a2b);
#pragma unroll
    for (int n = 2; n <= 16; ++n) Ep[n] = Ep[n >> 1] * Ep[n - (n >> 1)];
#pragma unroll
    for (int n = 0; n < 16; ++n) {
      pbuf[base + n * 384] = Ep[n + 1];
      hend[base + n * 384] = h[n];
    }
  } else {                                 // generic A fallback
    float a2[16];
#pragma unroll
    for (int n = 0; n < 16; ++n) a2[n] = a2f[d * 16 + n];
    for (int tt = 0; tt < tmax; ++tt) {
      const size_t r = (size_t)(r0 + tt);
      const float dtv = bf(dt[r * 384 + d]);
      const float xv  = bf(xcio[r * 384 + d]);
      sdt += dtv;
      const float dtx = dtv * xv;
      float4 bq[4], cq[4];
#pragma unroll
      for (int q = 0; q < 4; ++q) {
        bq[q] = *(const float4*)&lBC[tt * 32 + q * 4];
        cq[q] = *(const float4*)&lBC[tt * 32 + 16 + q * 4];
      }
      float y = 0.f;
#pragma unroll
      for (int n = 0; n < 16; ++n) {
        h[n] = h[n] * exp2f(dtv * a2[n]) + dtx * (&bq[n >> 2].x)[n & 3];
        y += h[n] * (&cq[n >> 2].x)[n & 3];
      }
      y += Dd * xv;
      xcio[r * 384 + d] = __float2bfloat16(y);
    }
#pragma unroll
    for (int n = 0; n < 16; ++n) {
      pbuf[base + n * 384] = exp2f(sdt * a2[n]);
      hend[base + n * 384] = h[n];
    }
  }
}

// ---------------------------------------------------------------------------
// scan phase 2: cross-chunk scan per (b,d,n); rewrites pbuf with h_start
// ---------------------------------------------------------------------------
__global__ void scan2_k(float* __restrict__ pbuf, const float* __restrict__ hend) {
  const int tid = blockIdx.x * 256 + threadIdx.x;   // 49152 total
  const int d = tid % 384;
  const int n = (tid / 384) & 15;
  const int b = tid / 6144;
  float H = 0.f;
  for (int c = 0; c < NCH; ++c) {
    const size_t idx = ((size_t)(c * 8 + b) * 16 + n) * 384 + d;
    const float p = pbuf[idx];
    const float he = hend[idx];
    pbuf[idx] = H;
    H = p * H + he;
  }
}

// ---------------------------------------------------------------------------
// scan phase 3 (light): y(t) = y_local(t) + sum_n C(t,n)*W^(n+1)*h_start[n]
// with W = exp2(sdt*a2b) on the geometric path; fused z-conv + silu gate.
// ---------------------------------------------------------------------------
__global__ __launch_bounds__(128)
void scan3_k(__hip_bfloat16* dtyg, const float* __restrict__ bc,
             const __hip_bfloat16* __restrict__ yl,
             const __hip_bfloat16* __restrict__ zh,
             const __hip_bfloat16* __restrict__ czw,
             const float* __restrict__ a2f,
             const float* __restrict__ hstart,
             const int* __restrict__ flagp)
{
  __shared__ __align__(16) float lC[CH * 16];
  const int blk = blockIdx.x;
  const int dt3 = blk % 3;
  const int c   = (blk / 3) % NCH;
  const int b   = blk / (3 * NCH);
  const int d   = dt3 * 128 + threadIdx.x;
  const int t0  = c * CH;
  const int r0  = b * L_ + t0;
  const int tmax = (L_ - t0 < CH) ? (L_ - t0) : CH;
  for (int i = threadIdx.x; i < tmax * 16; i += 128)
    lC[i] = bc[(size_t)r0 * 32 + (i >> 4) * 32 + 16 + (i & 15)];
  __syncthreads();

  float hs_[16];
  const size_t base = ((size_t)(c * 8 + b) * 16) * 384 + d;
#pragma unroll
  for (int n = 0; n < 16; ++n) hs_[n] = hstart[base + n * 384];
  float cw[4];
#pragma unroll
  for (int k = 0; k < 4; ++k) cw[k] = bf(czw[d * 4 + k]);

  float zm1 = (t0 - 1 >= 0) ? bf(zh[(size_t)(r0 - 1) * 384 + d]) : 0.f;
  float z0  = bf(zh[(size_t)r0 * 384 + d]);
  float zp1 = (t0 + 1 < L_) ? bf(zh[(size_t)(r0 + 1) * 384 + d]) : 0.f;
  float sdt = 0.f;

  if (flagp[1]) {                          // geometric A fast path
    const float a2b = a2f[d * 16];
    for (int tt = 0; tt < tmax; ++tt) {
      const int t = t0 + tt;
      const size_t r = (size_t)(r0 + tt);
      const float zp2 = (t + 2 < L_) ? bf(zh[(r + 2) * 384 + d]) : 0.f;
      const float dtv = bf(dtyg[r * 384 + d]);
      sdt += dtv;
      float pw[17];
      pw[1] = exp2f(sdt * a2b);
#pragma unroll
      for (int n = 2; n <= 16; ++n) pw[n] = pw[n >> 1] * pw[n - (n >> 1)];
      float4 cq[4];
#pragma unroll
      for (int q = 0; q < 4; ++q) cq[q] = *(const float4*)&lC[tt * 16 + q * 4];
      float corr = 0.f;
#pragma unroll
      for (int n = 0; n < 16; ++n)
        corr += (&cq[n >> 2].x)[n & 3] * hs_[n] * pw[n + 1];
      const float y = bf(yl[r * 384 + d]) + corr;
      const float zc = cw[0] * zm1 + cw[1] * z0 + cw[2] * zp1 + cw[3] * zp2;
      const float zs = zc / (1.f + __expf(-zc));
      dtyg[r * 384 + d] = __float2bfloat16(y * zs);
      zm1 = z0; z0 = zp1; zp1 = zp2;
    }
  } else {                                 // generic A fallback
    float a2[16];
#pragma unroll
    for (int n = 0; n < 16; ++n) a2[n] = a2f[d * 16 + n];
    for (int tt = 0; tt < tmax; ++tt) {
      const int t = t0 + tt;
      const size_t r = (size_t)(r0 + tt);
      const float zp2 = (t + 2 < L_) ? bf(zh[(r + 2) * 384 + d]) : 0.f;
      const float dtv = bf(dtyg[r * 384 + d]);
      sdt += dtv;
      float4 cq[4];
#pragma unroll
      for (int q = 0; q < 4; ++q) cq[q] = *(const float4*)&lC[tt * 16 + q * 4];
      float corr = 0.f;
#pragma unroll
      for (int n = 0; n < 16; ++n)
        corr += (&cq[n >> 2].x)[n & 3] * hs_[n] * exp2f(sdt * a2[n]);
      const float y = bf(yl[r * 384 + d]) + corr;
      const float zc = cw[0] * zm1 + cw[1] * z0 + cw[2] * zp1 + cw[3] * zp2;
      const float zs = zc / (1.f + __expf(-zc));
      dtyg[r * 384 + d] = __float2bfloat16(y * zs);
      zm1 = z0; z0 = zp1; zp1 = zp2;
    }
  }
}

// ---------------------------------------------------------------------------
extern "C" void kernel_launch(void* const* d_in, const int* in_sizes, int n_in,
                              void* d_out, int out_size, void* d_ws, size_t ws_size,
                              hipStream_t stream) {
  const void* hs   = d_in[0];
  const void* w_in = d_in[1];
  const void* cxw  = d_in[2];
  const void* czw  = d_in[3];
  const void* xw   = d_in[4];
  const void* dtw  = d_in[5];
  const void* dtb  = d_in[6];
  const void* alog = d_in[7];
  const void* dpar = d_in[8];
  const void* ow   = d_in[9];
  const int* perm  = (const int*)d_in[10];
  const int* permr = (const int*)d_in[11];

  char* ws = (char*)d_ws;
  size_t off = 0;
  auto alloc = [&](size_t nbytes) -> char* {
    char* p = ws + off;
    off += (nbytes + 255) & ~(size_t)255;
    return p;
  };
  int* flag              = (int*)alloc(256);
  int* nperm             = (int*)alloc(4096 * 4);
  int* npermr            = (int*)alloc(4096 * 4);
  float* a2f             = (float*)alloc(6144 * 4);
  __hip_bfloat16* w_inb  = (__hip_bfloat16*)alloc(294912 * 2);
  __hip_bfloat16* cxwb   = (__hip_bfloat16*)alloc(1536 * 2);
  __hip_bfloat16* czwb   = (__hip_bfloat16*)alloc(1536 * 2);
  __hip_bfloat16* xwb    = (__hip_bfloat16*)alloc(21504 * 2);
  __hip_bfloat16* dtwb   = (__hip_bfloat16*)alloc(9216 * 2);
  __hip_bfloat16* dtbb   = (__hip_bfloat16*)alloc(384 * 2);
  __hip_bfloat16* dparb  = (__hip_bfloat16*)alloc(384 * 2);
  __hip_bfloat16* owb    = (__hip_bfloat16*)alloc(147456 * 2);
  __hip_bfloat16* wcombb = (__hip_bfloat16*)alloc((size_t)512 * 384 * 2);
  __hip_bfloat16* hsb    = (__hip_bfloat16*)alloc((size_t)MTOT * 384 * 2);  // 25.2 MB
  __hip_bfloat16* zh     = (__hip_bfloat16*)alloc((size_t)MTOT * 384 * 2);  // 25.2 MB
  __hip_bfloat16* xc     = (__hip_bfloat16*)alloc((size_t)MTOT * 384 * 2);  // 25.2 MB
  __hip_bfloat16* dtyg   = (__hip_bfloat16*)alloc((size_t)MTOT * 384 * 2);  // 25.2 MB
  float*          bcf    = (float*)alloc((size_t)MTOT * 32 * 4);            // 4.2 MB
  // d_out as scratch: xh (bf16, dies at convx), then pbuf+hend (33.8 MB of 50.3)
  __hip_bfloat16* xh   = (__hip_bfloat16*)d_out;
  float*          pbuf = (float*)d_out;
  float*          hend = (float*)((char*)d_out + (size_t)NCH * B_ * NS * DH * 4);

  // 0) dtype + perm + A-structure normalization
  flag_k<<<1, 64, 0, stream>>>(hs, flag);
  perm_k<<<2, 1024, 0, stream>>>(perm, permr, nperm, npermr);
  a2prep_k<<<1, 384, 0, stream>>>(alog, a2f, flag);
  NormSet ns;
  ns.src[0] = w_in; ns.dst[0] = w_inb; ns.n[0] = 294912;
  ns.src[1] = ow;   ns.dst[1] = owb;   ns.n[1] = 147456;
  ns.src[2] = xw;   ns.dst[2] = xwb;   ns.n[2] = 21504;
  ns.src[3] = dtw;  ns.dst[3] = dtwb;  ns.n[3] = 9216;
  ns.src[4] = cxw;  ns.dst[4] = cxwb;  ns.n[4] = 1536;
  ns.src[5] = czw;  ns.dst[5] = czwb;  ns.n[5] = 1536;
  ns.src[6] = dtb;  ns.dst[6] = dtbb;  ns.n[6] = 384;
  ns.src[7] = dpar; ns.dst[7] = dparb; ns.n[7] = 384;
  norm_all<<<1152, 256, 0, stream>>>(ns, flag);
  // 1) fused dt/BC weight build
  prep_k<<<768, 256, 0, stream>>>(dtwb, xwb, wcombb);
  // 2) fused perm-gather + bf16 convert of hidden_states
  cvt_k<<<(MTOT * 48 + 255) / 256, 256, 0, stream>>>(hs, hsb, nperm, flag);
  // 3) in_proj MFMA GEMM (m97 structure) -> xh (d_out), zh
  gemm_k<0, 0><<<dim3(6, 257), 256, 0, stream>>>(
      hsb, w_inb, xh, zh, nullptr, nullptr, flag, MTOT, 768);
  // 4) depthwise conv + silu on x half (8 ch/thread)
  convx_k<<<(MTOT * 48 + 255) / 256, 256, 0, stream>>>(xh, cxwb, xc);
  // 5) fused dt (bias+fast-softplus, bf16) and B/C (fp32) MFMA GEMM
  gemm_k<0, 1><<<dim3(4, 257), 256, 0, stream>>>(
      xc, wcombb, dtyg, bcf, dtbb, nullptr, flag, MTOT, 512);
  // 6) chunked selective scan (y_local in phase 1; light correction phase 3)
  scan1_k<<<B_ * NCH * 3, 128, 0, stream>>>(dtyg, bcf, xc, a2f, dparb, pbuf, hend, flag);
  scan2_k<<<192, 256, 0, stream>>>(pbuf, hend);
  scan3_k<<<B_ * NCH * 3, 128, 0, stream>>>(dtyg, bcf, xc, zh, czwb, a2f, pbuf, flag);
  // 7) out_proj MFMA GEMM with inverse-perm gather -> final output
  gemm_k<1, 2><<<dim3(3, 257), 256, 0, stream>>>(
      dtyg, owb, d_out, nullptr, nullptr, npermr, flag, MTOT, 384);
  (void)in_sizes; (void)n_in; (void)out_size; (void)ws_size;
}

// Round 6
// 330.635 us; speedup vs baseline: 1.9212x; 1.1630x over previous
//
#include <hip/hip_runtime.h>
#include <hip/hip_bf16.h>

#define DEVI __device__ __forceinline__

constexpr int B_   = 8;
constexpr int L_   = 4097;
constexpr int MTOT = B_ * L_;          // 32776 tokens
constexpr int DH   = 384;              // d_half
constexpr int NS   = 16;               // d_state
constexpr int CH   = 33;               // scan chunk (r13: 48->33, 16->23 waves/CU;
                                       // 2 x 24.58 MB pbuf/hend still fit in d_out)
constexpr int NCH  = (L_ + CH - 1) / CH;  // 125 chunks (last has 5 tokens)

typedef __bf16 bf16x8 __attribute__((ext_vector_type(8)));
typedef float  f32x4  __attribute__((ext_vector_type(4)));

DEVI float bl(unsigned v) { return __uint_as_float(v << 16); }          // low bf16
DEVI float bh(unsigned v) { return __uint_as_float(v & 0xffff0000u); }  // high bf16
DEVI float bf(const __hip_bfloat16 x) { return __bfloat162float(x); }
DEVI unsigned short f2bu(float x) {
  __hip_bfloat16 b = __float2bfloat16(x);
  return *(unsigned short*)&b;
}
DEVI float u16f(const uint4& u, int j) {   // element j (0..7) of 8 packed bf16
  const unsigned w = (&u.x)[j >> 1];
  return (j & 1) ? bh(w) : bl(w);
}
// fast softplus: 2 HW transcendentals vs log1pf's ~30-instr libm sequence
DEVI float softplus_f(float x) {
  return (x > 20.f) ? x : __logf(1.f + __expf(x));
}

// global -> LDS direct (16B per lane). LDS dest must be wave-uniform + lane*16.
DEVI void gld16(const __hip_bfloat16* g, __hip_bfloat16* l) {
  __builtin_amdgcn_global_load_lds(
      (const __attribute__((address_space(1))) void*)g,
      (__attribute__((address_space(3))) void*)l, 16, 0, 0);
}

// ---------------------------------------------------------------------------
// dtype detector; flag[1] = geometric-A structure flag.
// ---------------------------------------------------------------------------
__global__ void flag_k(const void* hs, int* flagp) {
  if (threadIdx.x == 0 && blockIdx.x == 0) {
    const unsigned short* u = (const unsigned short*)hs;
    int ok = 1;
    for (int i = 0; i < 8; ++i) {
      const unsigned short v = u[2 * i];
      const int e = (v >> 7) & 0xFF;
      if (!(v == 0 || (e >= 100 && e <= 140))) ok = 0;
    }
    flagp[0] = ok;
    flagp[1] = 1;
  }
}

// ---------------------------------------------------------------------------
// a2prep_k: a2[d][n] = -log2(e)*exp(A_log[d][n]) fp32 + geometric check.
// ---------------------------------------------------------------------------
__global__ void a2prep_k(const void* __restrict__ alog, float* __restrict__ a2fo,
                         int* flagp) {
  const int d = threadIdx.x;             // 384 threads, one d each
  const int f = flagp[0];
  float a2[16];
#pragma unroll
  for (int n = 0; n < 16; ++n) {
    const float v = f ? bf(((const __hip_bfloat16*)alog)[d * 16 + n])
                      : ((const float*)alog)[d * 16 + n];
    a2[n] = -1.4426950408889634f * __expf(v);
    a2fo[d * 16 + n] = a2[n];
  }
  int ok = 1;
#pragma unroll
  for (int n = 1; n < 16; ++n) {
    const float ref = (float)(n + 1) * a2[0];
    if (fabsf(a2[n] - ref) > 1e-3f * fabsf(ref)) ok = 0;
  }
  if (!ok) atomicAnd(&flagp[1], 0);
}

// ---------------------------------------------------------------------------
// perm normalizer: int64 storage has all odd int32 words zero (values<4096).
// ---------------------------------------------------------------------------
__global__ void perm_k(const int* p0, const int* p1, int* d0, int* d1) {
  __shared__ int s_or;
  const int* src = blockIdx.x ? p1 : p0;
  int*       dst = blockIdx.x ? d1 : d0;
  if (threadIdx.x == 0) s_or = 0;
  __syncthreads();
  int loc = 0;
  for (int i = threadIdx.x; i < 2048; i += 1024) loc |= src[2 * i + 1];
  atomicOr(&s_or, loc);
  __syncthreads();
  const bool is64 = (s_or == 0);
  for (int j = threadIdx.x; j < 4096; j += 1024)
    dst[j] = is64 ? (int)((const long long*)src)[j] : src[j];
}

// ---------------------------------------------------------------------------
// fused normalization of weight tensors to bf16 (one launch)
// ---------------------------------------------------------------------------
struct NormSet { const void* src[8]; void* dst[8]; int n[8]; };
__global__ void norm_all(NormSet s, const int* flagp) {
  const int idx = blockIdx.x * 256 + threadIdx.x;
  const int f = flagp[0];
#pragma unroll
  for (int t = 0; t < 8; ++t) {
    if (idx < s.n[t]) {
      __hip_bfloat16* d = (__hip_bfloat16*)s.dst[t];
      if (f) d[idx] = ((const __hip_bfloat16*)s.src[t])[idx];
      else   d[idx] = __float2bfloat16(((const float*)s.src[t])[idx]);
    }
  }
}

// ---------------------------------------------------------------------------
// Wcomb bf16 (512 x 384): rows 0..383 = dt_proj_w @ x_proj_w[0:24],
// rows 384..415 = x_proj_w[24:56] (B then C), rows 416..511 = 0.
// ---------------------------------------------------------------------------
__global__ void prep_k(const __hip_bfloat16* __restrict__ dtw,
                       const __hip_bfloat16* __restrict__ xw,
                       __hip_bfloat16* __restrict__ wcomb) {
  const int idx = blockIdx.x * 256 + threadIdx.x;
  if (idx >= 512 * 384) return;
  const int n = idx / 384, k = idx - n * 384;
  float v = 0.f;
  if (n < 384) {
#pragma unroll
    for (int r = 0; r < 24; ++r) v += bf(dtw[n * 24 + r]) * bf(xw[r * 384 + k]);
  } else if (n < 416) {
    v = bf(xw[(24 + n - 384) * 384 + k]);
  }
  wcomb[idx] = __float2bfloat16(v);
}

// ---------------------------------------------------------------------------
// cvt_k: fused perm-gather + dtype-normalize of hidden_states into bf16 hsb.
// ---------------------------------------------------------------------------
__global__ void cvt_k(const void* __restrict__ hs, __hip_bfloat16* __restrict__ dst,
                      const int* __restrict__ gidx, const int* __restrict__ flagp) {
  const int idx = blockIdx.x * 256 + threadIdx.x;
  if (idx >= MTOT * 48) return;
  const int j = idx % 48;        // 8-elem group within row
  const int r = idx / 48;        // destination (reordered) token row
  const int b = r / L_, t = r - b * L_;
  const int src = b * L_ + (t == 0 ? 0 : 1 + gidx[t - 1]);
  uint4 o;
  if (flagp[0]) {
    o = *(const uint4*)((const __hip_bfloat16*)hs + (size_t)src * 384 + j * 8);
  } else {
    const float* f = (const float*)hs + (size_t)src * 384 + j * 8;
    const float4 f0 = *(const float4*)f;
    const float4 f1 = *(const float4*)(f + 4);
    o.x = f2bu(f0.x) | ((unsigned)f2bu(f0.y) << 16);
    o.y = f2bu(f0.z) | ((unsigned)f2bu(f0.w) << 16);
    o.z = f2bu(f1.x) | ((unsigned)f2bu(f1.y) << 16);
    o.w = f2bu(f1.z) | ((unsigned)f2bu(f1.w) << 16);
  }
  *(uint4*)(dst + (size_t)r * 384 + j * 8) = o;
}

// ---------------------------------------------------------------------------
// MFMA GEMM: 128x128 tile, K=384 = 6 x BK64 (half the barriers of BK32),
// staging via global_load_lds w=16 into [kh][128][32] LDS layout (the free
// per-lane GLOBAL source keeps rows at 64B stride -- a flat [128][64] layout
// would be a 16-way bank conflict on fragment ds_reads). Epilogue via
// LDS-transposed 2-pass coalesced 16B stores (was 64 scattered 2-4B stores
// per thread). Bijective XCD-contiguous tile remap kept.
// ---------------------------------------------------------------------------
template<int GATHER, int EPI>
__global__ __launch_bounds__(256, 3)
void gemm_k(const __hip_bfloat16* __restrict__ A, const __hip_bfloat16* __restrict__ W,
            void* __restrict__ e0, void* __restrict__ e1,
            const __hip_bfloat16* __restrict__ bias,
            const int* __restrict__ gidx, const int* __restrict__ flagp,
            int M, int N)
{
  __shared__ __align__(16) char smem[36864];   // staging 32KB | lT 18.4/36.9KB
  __hip_bfloat16* lA = (__hip_bfloat16*)smem;  // [2][128][32] bf16
  __hip_bfloat16* lB = lA + 2 * 128 * 32;
  const int tid  = threadIdx.x;
  const int lane = tid & 63;
  const int wv   = tid >> 6;
  const int wm   = wv >> 1, wn = wv & 1;
  const int lrow = lane & 15, quad = lane >> 4;
  const int fbf  = flagp[0];              // 1 = bf16 external storage

  const int NT = gridDim.x;
  const int nblocks = NT * (int)gridDim.y;
  const int id = blockIdx.y * NT + blockIdx.x;
  const int q8 = nblocks >> 3, r8 = nblocks & 7;
  const int xcd = id & 7, slot = id >> 3;
  const int nid = (xcd < r8 ? xcd * (q8 + 1)
                            : r8 * (q8 + 1) + (xcd - r8) * q8) + slot;
  const int mt = nid / NT, nt = nid - mt * NT;

  // wave whose whole 64-col band is Wcomb zero-pad: skip fragment+MFMA work
  const bool live = !(EPI == 1 && nt * 128 + wn * 64 >= 416);

  // staging map: flat 16B slot s -> (kh = s>>9, row = (s>>2)&127, c = s&3);
  // LDS dest linear in s (gld_lds constraint); global src permuted to match.
  const __hip_bfloat16* aSrc[4];
  const __hip_bfloat16* bSrc[4];
  __hip_bfloat16* aDst[4];
  __hip_bfloat16* bDst[4];
#pragma unroll
  for (int p = 0; p < 4; ++p) {
    const int s   = p * 256 + tid;
    const int kh  = s >> 9;
    const int row = (s >> 2) & 127;
    const int kc  = kh * 32 + (s & 3) * 8;   // K offset within BK=64
    int r = mt * 128 + row;
    if (r >= M) r = M - 1;                   // tail tile: duplicate a valid row
    int src;
    if (GATHER) { const int b = r / L_, t = r - b * L_;
                  src = b * L_ + (t == 0 ? 0 : 1 + gidx[t - 1]); }
    else        { src = r; }
    aSrc[p] = A + (size_t)src * 384 + kc;
    bSrc[p] = W + (size_t)(nt * 128 + row) * 384 + kc;
    aDst[p] = &lA[s * 8];
    bDst[p] = &lB[s * 8];
  }

  f32x4 acc[4][4] = {};

#pragma unroll
  for (int kt = 0; kt < 6; ++kt) {         // K = 6 * 64
    __syncthreads();                       // WAR: prior ds_reads done
#pragma unroll
    for (int p = 0; p < 4; ++p) gld16(aSrc[p] + kt * 64, aDst[p]);
#pragma unroll
    for (int p = 0; p < 4; ++p) gld16(bSrc[p] + kt * 64, bDst[p]);
    __syncthreads();                       // staged data visible
    if (live) {
#pragma unroll
      for (int kh = 0; kh < 2; ++kh) {
        bf16x8 af[4], bfr[4];
#pragma unroll
        for (int i = 0; i < 4; ++i)
          af[i] = *reinterpret_cast<const bf16x8*>(
              &lA[kh * 4096 + (wm * 64 + i * 16 + lrow) * 32 + quad * 8]);
#pragma unroll
        for (int j = 0; j < 4; ++j)
          bfr[j] = *reinterpret_cast<const bf16x8*>(
              &lB[kh * 4096 + (wn * 64 + j * 16 + lrow) * 32 + quad * 8]);
#pragma unroll
        for (int i = 0; i < 4; ++i)
#pragma unroll
          for (int j = 0; j < 4; ++j)
            acc[i][j] = __builtin_amdgcn_mfma_f32_16x16x32_bf16(af[i], bfr[j], acc[i][j], 0, 0, 0);
      }
    }
  }

  // ---- epilogue (acc[i][j][rg] = C[row=quad*4+rg(+i*16+wm*64)][col=lrow(+j*16+wn*64)])
  const int r0c = mt * 128;
  if (EPI == 1 && nt == 3) {
    // scalar B/C path (cols 384..415, fp32)
#pragma unroll
    for (int i = 0; i < 4; ++i) {
      const int row0 = r0c + wm * 64 + i * 16 + quad * 4;
#pragma unroll
      for (int j = 0; j < 4; ++j) {
        const int col = 384 + wn * 64 + j * 16 + lrow;
        if (col >= 416) continue;
#pragma unroll
        for (int rg = 0; rg < 4; ++rg) {
          const int r = row0 + rg;
          if (r >= M) continue;
          ((float*)e1)[(size_t)r * 32 + (col - 384)] = acc[i][j][rg];
        }
      }
    }
  } else if (EPI == 2 && !fbf) {
    // fp32 out: 2-pass LDS transpose ([128][72] f32), coalesced 16B stores
    float* lT = (float*)smem;
#pragma unroll
    for (int h = 0; h < 2; ++h) {
      __syncthreads();
      if (wn == h) {
#pragma unroll
        for (int i = 0; i < 4; ++i)
#pragma unroll
          for (int j = 0; j < 4; ++j)
#pragma unroll
            for (int rg = 0; rg < 4; ++rg)
              lT[(wm * 64 + i * 16 + quad * 4 + rg) * 72 + j * 16 + lrow] = acc[i][j][rg];
      }
      __syncthreads();
#pragma unroll
      for (int p = 0; p < 8; ++p) {
        const int ch = p * 256 + tid;      // 2048 x 16B chunks
        const int row = ch >> 4, c4 = (ch & 15) * 4;
        const int r = r0c + row;
        if (r < M) {
          const float4 v = *(const float4*)&lT[row * 72 + c4];
          *(float4*)((float*)e0 + (size_t)r * 384 + nt * 128 + h * 64 + c4) = v;
        }
      }
    }
  } else {
    // bf16: 2-pass LDS transpose ([128][72] bf16), coalesced 16B stores.
    // EPI=0 plain; EPI=1 nt<3 softplus+bias; EPI=2 fbf plain.
    __hip_bfloat16* lT = (__hip_bfloat16*)smem;
#pragma unroll
    for (int h = 0; h < 2; ++h) {
      __syncthreads();
      if (wn == h) {
        float bj[4] = {};
        if (EPI == 1) {
#pragma unroll
          for (int j = 0; j < 4; ++j)
            bj[j] = bf(bias[nt * 128 + h * 64 + j * 16 + lrow]);
        }
#pragma unroll
        for (int i = 0; i < 4; ++i)
#pragma unroll
          for (int j = 0; j < 4; ++j)
#pragma unroll
            for (int rg = 0; rg < 4; ++rg) {
              float v = acc[i][j][rg];
              if (EPI == 1) v = softplus_f(v + bj[j]);
              lT[(wm * 64 + i * 16 + quad * 4 + rg) * 72 + j * 16 + lrow] =
                  __float2bfloat16(v);
            }
      }
      __syncthreads();
#pragma unroll
      for (int p = 0; p < 4; ++p) {
        const int ch = p * 256 + tid;      // 1024 x 16B chunks
        const int row = ch >> 3, c8 = (ch & 7) * 8;
        const int r = r0c + row;
        if (r < M) {
          const uint4 v = *(const uint4*)&lT[row * 72 + c8];
          const int g = nt * 128 + h * 64 + c8;
          __hip_bfloat16* dst = (EPI == 0 && g >= 384)
                ? (__hip_bfloat16*)e1 + (size_t)r * 384 + (g - 384)
                : (__hip_bfloat16*)e0 + (size_t)r * 384 + g;
          *(uint4*)dst = v;
        }
      }
    }
  }
}

// ---------------------------------------------------------------------------
// depthwise conv k=4 (taps t-1..t+2) + silu on x half; 8 channels/thread.
// ---------------------------------------------------------------------------
__global__ void convx_k(const __hip_bfloat16* __restrict__ xh,
                        const __hip_bfloat16* __restrict__ cxw,
                        __hip_bfloat16* __restrict__ xc) {
  const int idx = blockIdx.x * 256 + threadIdx.x;
  if (idx >= MTOT * 48) return;
  const int g  = idx % 48;       // channel group (8 ch)
  const int rg = idx / 48;       // token row
  const int t  = rg % L_;
  const int c0 = g * 8;
  uint4 wv[4];                   // weights: channels c0..c0+7 x 4 taps
#pragma unroll
  for (int p = 0; p < 4; ++p) wv[p] = *(const uint4*)(cxw + c0 * 4 + p * 8);
  float acc[8] = {};
#pragma unroll
  for (int k = 0; k < 4; ++k) {
    const int tt = t + k - 1;
    if (tt < 0 || tt >= L_) continue;
    const uint4 u = *(const uint4*)(xh + (size_t)(rg + k - 1) * 384 + c0);
#pragma unroll
    for (int j = 0; j < 8; ++j) {
      const int e = j * 4 + k;                      // weight flat element
      acc[j] += u16f(wv[e >> 3], e & 7) * u16f(u, j);
    }
  }
  uint4 o;
#pragma unroll
  for (int p = 0; p < 4; ++p) {
    const float s0 = acc[2 * p]     / (1.f + __expf(-acc[2 * p]));
    const float s1 = acc[2 * p + 1] / (1.f + __expf(-acc[2 * p + 1]));
    (&o.x)[p] = f2bu(s0) | ((unsigned)f2bu(s1) << 16);
  }
  *(uint4*)(xc + (size_t)rg * 384 + c0) = o;
}

// ---------------------------------------------------------------------------
// scan phase 1: per (b, chunk, d) local scan with h0=0. Geometric-A fast
// path: ONE exp2 per timestep + log-depth power tree. y accumulated in two
// chains (halved serial fma dependency). y_local IN PLACE over xc.
// ---------------------------------------------------------------------------
__global__ __launch_bounds__(128)
void scan1_k(const __hip_bfloat16* __restrict__ dt, const float* __restrict__ bc,
             __hip_bfloat16* xcio,
             const float* __restrict__ a2f,
             const __hip_bfloat16* __restrict__ dpar,
             float* __restrict__ pbuf, float* __restrict__ hend,
             const int* __restrict__ flagp)
{
  __shared__ __align__(16) float lBC[CH * 32];
  const int blk = blockIdx.x;
  const int dt3 = blk % 3;
  const int c   = (blk / 3) % NCH;
  const int b   = blk / (3 * NCH);
  const int d   = dt3 * 128 + threadIdx.x;
  const int t0  = c * CH;
  const int r0  = b * L_ + t0;
  const int tmax = (L_ - t0 < CH) ? (L_ - t0) : CH;
  for (int i = threadIdx.x; i < tmax * 32; i += 128) lBC[i] = bc[(size_t)r0 * 32 + i];
  __syncthreads();

  float h[16];
#pragma unroll
  for (int n = 0; n < 16; ++n) h[n] = 0.f;
  float sdt = 0.f;
  const float Dd = bf(dpar[d]);
  const size_t base = ((size_t)(c * 8 + b) * 16) * 384 + d;

  if (flagp[1]) {                          // geometric A: a2[n] = (n+1)*a2b
    const float a2b = a2f[d * 16];
    for (int tt = 0; tt < tmax; ++tt) {
      const size_t r = (size_t)(r0 + tt);
      const float dtv = bf(dt[r * 384 + d]);
      const float xv  = bf(xcio[r * 384 + d]);
      sdt += dtv;
      const float dtx = dtv * xv;
      float pw[17];
      pw[1] = exp2f(dtv * a2b);
#pragma unroll
      for (int n = 2; n <= 16; ++n) pw[n] = pw[n >> 1] * pw[n - (n >> 1)];
      float4 bq[4], cq[4];
#pragma unroll
      for (int q = 0; q < 4; ++q) {
        bq[q] = *(const float4*)&lBC[tt * 32 + q * 4];
        cq[q] = *(const float4*)&lBC[tt * 32 + 16 + q * 4];
      }
      float ya = 0.f, yb = 0.f;
#pragma unroll
      for (int n = 0; n < 16; ++n) {
        h[n] = h[n] * pw[n + 1] + dtx * (&bq[n >> 2].x)[n & 3];
        const float t = h[n] * (&cq[n >> 2].x)[n & 3];
        if (n & 1) yb += t; else ya += t;
      }
      const float y = ya + yb + Dd * xv;
      xcio[r * 384 + d] = __float2bfloat16(y);
    }
    float Ep[17];
    Ep[1] = exp2f(sdt * a2b);
#pragma unroll
    for (int n = 2; n <= 16; ++n) Ep[n] = Ep[n >> 1] * Ep[n - (n >> 1)];
#pragma unroll
    for (int n = 0; n < 16; ++n) {
      pbuf[base + n * 384] = Ep[n + 1];
      hend[base + n * 384] = h[n];
    }
  } else {                                 // generic A fallback
    float a2[16];
#pragma unroll
    for (int n = 0; n < 16; ++n) a2[n] = a2f[d * 16 + n];
    for (int tt = 0; tt < tmax; ++tt) {
      const size_t r = (size_t)(r0 + tt);
      const float dtv = bf(dt[r * 384 + d]);
      const float xv  = bf(xcio[r * 384 + d]);
      sdt += dtv;
      const float dtx = dtv * xv;
      float4 bq[4], cq[4];
#pragma unroll
      for (int q = 0; q < 4; ++q) {
        bq[q] = *(const float4*)&lBC[tt * 32 + q * 4];
        cq[q] = *(const float4*)&lBC[tt * 32 + 16 + q * 4];
      }
      float ya = 0.f, yb = 0.f;
#pragma unroll
      for (int n = 0; n < 16; ++n) {
        h[n] = h[n] * exp2f(dtv * a2[n]) + dtx * (&bq[n >> 2].x)[n & 3];
        const float t = h[n] * (&cq[n >> 2].x)[n & 3];
        if (n & 1) yb += t; else ya += t;
      }
      const float y = ya + yb + Dd * xv;
      xcio[r * 384 + d] = __float2bfloat16(y);
    }
#pragma unroll
    for (int n = 0; n < 16; ++n) {
      pbuf[base + n * 384] = exp2f(sdt * a2[n]);
      hend[base + n * 384] = h[n];
    }
  }
}

// ---------------------------------------------------------------------------
// scan phase 2: cross-chunk scan per (b,d,n); rewrites pbuf with h_start
// ---------------------------------------------------------------------------
__global__ void scan2_k(float* __restrict__ pbuf, const float* __restrict__ hend) {
  const int tid = blockIdx.x * 256 + threadIdx.x;   // 49152 total
  const int d = tid % 384;
  const int n = (tid / 384) & 15;
  const int b = tid / 6144;
  float H = 0.f;
  for (int c = 0; c < NCH; ++c) {
    const size_t idx = ((size_t)(c * 8 + b) * 16 + n) * 384 + d;
    const float p = pbuf[idx];
    const float he = hend[idx];
    pbuf[idx] = H;
    H = p * H + he;
  }
}

// ---------------------------------------------------------------------------
// scan phase 3 (light): y(t) = y_local(t) + sum_n C(t,n)*W^(n+1)*h_start[n];
// fused z-conv + silu gate; corr in two chains. IN PLACE over dt (dtyg).
// ---------------------------------------------------------------------------
__global__ __launch_bounds__(128)
void scan3_k(__hip_bfloat16* dtyg, const float* __restrict__ bc,
             const __hip_bfloat16* __restrict__ yl,
             const __hip_bfloat16* __restrict__ zh,
             const __hip_bfloat16* __restrict__ czw,
             const float* __restrict__ a2f,
             const float* __restrict__ hstart,
             const int* __restrict__ flagp)
{
  __shared__ __align__(16) float lC[CH * 16];
  const int blk = blockIdx.x;
  const int dt3 = blk % 3;
  const int c   = (blk / 3) % NCH;
  const int b   = blk / (3 * NCH);
  const int d   = dt3 * 128 + threadIdx.x;
  const int t0  = c * CH;
  const int r0  = b * L_ + t0;
  const int tmax = (L_ - t0 < CH) ? (L_ - t0) : CH;
  for (int i = threadIdx.x; i < tmax * 16; i += 128)
    lC[i] = bc[(size_t)r0 * 32 + (i >> 4) * 32 + 16 + (i & 15)];
  __syncthreads();

  float hs_[16];
  const size_t base = ((size_t)(c * 8 + b) * 16) * 384 + d;
#pragma unroll
  for (int n = 0; n < 16; ++n) hs_[n] = hstart[base + n * 384];
  float cw[4];
#pragma unroll
  for (int k = 0; k < 4; ++k) cw[k] = bf(czw[d * 4 + k]);

  float zm1 = (t0 - 1 >= 0) ? bf(zh[(size_t)(r0 - 1) * 384 + d]) : 0.f;
  float z0  = bf(zh[(size_t)r0 * 384 + d]);
  float zp1 = (t0 + 1 < L_) ? bf(zh[(size_t)(r0 + 1) * 384 + d]) : 0.f;
  float sdt = 0.f;

  if (flagp[1]) {                          // geometric A fast path
    const float a2b = a2f[d * 16];
    for (int tt = 0; tt < tmax; ++tt) {
      const int t = t0 + tt;
      const size_t r = (size_t)(r0 + tt);
      const float zp2 = (t + 2 < L_) ? bf(zh[(r + 2) * 384 + d]) : 0.f;
      const float dtv = bf(dtyg[r * 384 + d]);
      sdt += dtv;
      float pw[17];
      pw[1] = exp2f(sdt * a2b);
#pragma unroll
      for (int n = 2; n <= 16; ++n) pw[n] = pw[n >> 1] * pw[n - (n >> 1)];
      float4 cq[4];
#pragma unroll
      for (int q = 0; q < 4; ++q) cq[q] = *(const float4*)&lC[tt * 16 + q * 4];
      float ca = 0.f, cb = 0.f;
#pragma unroll
      for (int n = 0; n < 16; ++n) {
        const float t2 = (&cq[n >> 2].x)[n & 3] * hs_[n] * pw[n + 1];
        if (n & 1) cb += t2; else ca += t2;
      }
      const float y = bf(yl[r * 384 + d]) + ca + cb;
      const float zc = cw[0] * zm1 + cw[1] * z0 + cw[2] * zp1 + cw[3] * zp2;
      const float zs = zc / (1.f + __expf(-zc));
      dtyg[r * 384 + d] = __float2bfloat16(y * zs);
      zm1 = z0; z0 = zp1; zp1 = zp2;
    }
  } else {                                 // generic A fallback
    float a2[16];
#pragma unroll
    for (int n = 0; n < 16; ++n) a2[n] = a2f[d * 16 + n];
    for (int tt = 0; tt < tmax; ++tt) {
      const int t = t0 + tt;
      const size_t r = (size_t)(r0 + tt);
      const float zp2 = (t + 2 < L_) ? bf(zh[(r + 2) * 384 + d]) : 0.f;
      const float dtv = bf(dtyg[r * 384 + d]);
      sdt += dtv;
      float4 cq[4];
#pragma unroll
      for (int q = 0; q < 4; ++q) cq[q] = *(const float4*)&lC[tt * 16 + q * 4];
      float ca = 0.f, cb = 0.f;
#pragma unroll
      for (int n = 0; n < 16; ++n) {
        const float t2 = (&cq[n >> 2].x)[n & 3] * hs_[n] * exp2f(sdt * a2[n]);
        if (n & 1) cb += t2; else ca += t2;
      }
      const float y = bf(yl[r * 384 + d]) + ca + cb;
      const float zc = cw[0] * zm1 + cw[1] * z0 + cw[2] * zp1 + cw[3] * zp2;
      const float zs = zc / (1.f + __expf(-zc));
      dtyg[r * 384 + d] = __float2bfloat16(y * zs);
      zm1 = z0; z0 = zp1; zp1 = zp2;
    }
  }
}

// ---------------------------------------------------------------------------
extern "C" void kernel_launch(void* const* d_in, const int* in_sizes, int n_in,
                              void* d_out, int out_size, void* d_ws, size_t ws_size,
                              hipStream_t stream) {
  const void* hs   = d_in[0];
  const void* w_in = d_in[1];
  const void* cxw  = d_in[2];
  const void* czw  = d_in[3];
  const void* xw   = d_in[4];
  const void* dtw  = d_in[5];
  const void* dtb  = d_in[6];
  const void* alog = d_in[7];
  const void* dpar = d_in[8];
  const void* ow   = d_in[9];
  const int* perm  = (const int*)d_in[10];
  const int* permr = (const int*)d_in[11];

  char* ws = (char*)d_ws;
  size_t off = 0;
  auto alloc = [&](size_t nbytes) -> char* {
    char* p = ws + off;
    off += (nbytes + 255) & ~(size_t)255;
    return p;
  };
  int* flag              = (int*)alloc(256);
  int* nperm             = (int*)alloc(4096 * 4);
  int* npermr            = (int*)alloc(4096 * 4);
  float* a2f             = (float*)alloc(6144 * 4);
  __hip_bfloat16* w_inb  = (__hip_bfloat16*)alloc(294912 * 2);
  __hip_bfloat16* cxwb   = (__hip_bfloat16*)alloc(1536 * 2);
  __hip_bfloat16* czwb   = (__hip_bfloat16*)alloc(1536 * 2);
  __hip_bfloat16* xwb    = (__hip_bfloat16*)alloc(21504 * 2);
  __hip_bfloat16* dtwb   = (__hip_bfloat16*)alloc(9216 * 2);
  __hip_bfloat16* dtbb   = (__hip_bfloat16*)alloc(384 * 2);
  __hip_bfloat16* dparb  = (__hip_bfloat16*)alloc(384 * 2);
  __hip_bfloat16* owb    = (__hip_bfloat16*)alloc(147456 * 2);
  __hip_bfloat16* wcombb = (__hip_bfloat16*)alloc((size_t)512 * 384 * 2);
  __hip_bfloat16* hsb    = (__hip_bfloat16*)alloc((size_t)MTOT * 384 * 2);  // 25.2 MB
  __hip_bfloat16* zh     = (__hip_bfloat16*)alloc((size_t)MTOT * 384 * 2);  // 25.2 MB
  __hip_bfloat16* xc     = (__hip_bfloat16*)alloc((size_t)MTOT * 384 * 2);  // 25.2 MB
  __hip_bfloat16* dtyg   = (__hip_bfloat16*)alloc((size_t)MTOT * 384 * 2);  // 25.2 MB
  float*          bcf    = (float*)alloc((size_t)MTOT * 32 * 4);            // 4.2 MB
  // d_out (50.35 MB) as scratch: xh bf16 [0,25.2) dies at convx; then
  // pbuf [0,24.58) + hend [24.58,49.15) -- NCH=125 sized to fit both.
  __hip_bfloat16* xh   = (__hip_bfloat16*)d_out;
  float*          pbuf = (float*)d_out;
  float*          hend = (float*)((char*)d_out + (size_t)NCH * B_ * NS * DH * 4);

  // 0) dtype + perm + A-structure normalization
  flag_k<<<1, 64, 0, stream>>>(hs, flag);
  perm_k<<<2, 1024, 0, stream>>>(perm, permr, nperm, npermr);
  a2prep_k<<<1, 384, 0, stream>>>(alog, a2f, flag);
  NormSet ns;
  ns.src[0] = w_in; ns.dst[0] = w_inb; ns.n[0] = 294912;
  ns.src[1] = ow;   ns.dst[1] = owb;   ns.n[1] = 147456;
  ns.src[2] = xw;   ns.dst[2] = xwb;   ns.n[2] = 21504;
  ns.src[3] = dtw;  ns.dst[3] = dtwb;  ns.n[3] = 9216;
  ns.src[4] = cxw;  ns.dst[4] = cxwb;  ns.n[4] = 1536;
  ns.src[5] = czw;  ns.dst[5] = czwb;  ns.n[5] = 1536;
  ns.src[6] = dtb;  ns.dst[6] = dtbb;  ns.n[6] = 384;
  ns.src[7] = dpar; ns.dst[7] = dparb; ns.n[7] = 384;
  norm_all<<<1152, 256, 0, stream>>>(ns, flag);
  // 1) fused dt/BC weight build
  prep_k<<<768, 256, 0, stream>>>(dtwb, xwb, wcombb);
  // 2) fused perm-gather + bf16 convert of hidden_states
  cvt_k<<<(MTOT * 48 + 255) / 256, 256, 0, stream>>>(hs, hsb, nperm, flag);
  // 3) in_proj MFMA GEMM -> xh (d_out), zh
  gemm_k<0, 0><<<dim3(6, 257), 256, 0, stream>>>(
      hsb, w_inb, xh, zh, nullptr, nullptr, flag, MTOT, 768);
  // 4) depthwise conv + silu on x half (8 ch/thread)
  convx_k<<<(MTOT * 48 + 255) / 256, 256, 0, stream>>>(xh, cxwb, xc);
  // 5) fused dt (bias+fast-softplus, bf16) and B/C (fp32) MFMA GEMM
  gemm_k<0, 1><<<dim3(4, 257), 256, 0, stream>>>(
      xc, wcombb, dtyg, bcf, dtbb, nullptr, flag, MTOT, 512);
  // 6) chunked selective scan (y_local in phase 1; light correction phase 3)
  scan1_k<<<B_ * NCH * 3, 128, 0, stream>>>(dtyg, bcf, xc, a2f, dparb, pbuf, hend, flag);
  scan2_k<<<192, 256, 0, stream>>>(pbuf, hend);
  scan3_k<<<B_ * NCH * 3, 128, 0, stream>>>(dtyg, bcf, xc, zh, czwb, a2f, pbuf, flag);
  // 7) out_proj MFMA GEMM with inverse-perm gather -> final output
  gemm_k<1, 2><<<dim3(3, 257), 256, 0, stream>>>(
      dtyg, owb, d_out, nullptr, nullptr, npermr, flag, MTOT, 384);
  (void)in_sizes; (void)n_in; (void)out_size; (void)ws_size;
}